// Round 3
// baseline (987.143 us; speedup 1.0000x reference)
//
#include <hip/hip_runtime.h>
#include <hip/hip_bf16.h>
#include <cstdint>

// ---------------- constants ----------------
#define DIM     384
#define NHEADS  12
#define HD      32
#define HGRID   64          // H = W = 64
#define NTOK    64          // tokens per 8x8 window
#define MTOT    65536       // 16 * 4096 rows
#define HID     1536

typedef __attribute__((ext_vector_type(8))) short bf16x8;
typedef __attribute__((ext_vector_type(4))) float f32x4;
typedef __hip_bfloat16 bf16;

typedef __attribute__((address_space(1))) const void* as1_cvp;
typedef __attribute__((address_space(3))) void*       as3_vp;
#define GLDS16(g, l) __builtin_amdgcn_global_load_lds((as1_cvp)(g), (as3_vp)(l), 16, 0, 0)

// ---------------- K0: weight fp32 (KxN) -> bf16 transposed (NxK) ----------------
__global__ void wconv_kernel(const float* __restrict__ src, bf16* __restrict__ dst,
                             int K, int N) {
  int i = blockIdx.x * 256 + threadIdx.x;
  if (i >= K * N) return;
  int n = i / K, k = i - n * K;
  dst[i] = __float2bfloat16(src[(size_t)k * N + n]);
}

// ---------------- K1/K5: LayerNorm (optionally fused roll+window gather) ----------
// blockIdx.x = OUTPUT row; 384 threads = one per channel.
__global__ __launch_bounds__(384) void ln_kernel(const float* __restrict__ x,
    const float* __restrict__ g, const float* __restrict__ bta,
    bf16* __restrict__ out, int windowed) {
  const int row = blockIdx.x;
  const int c = threadIdx.x;
  size_t src;
  if (windowed) {
    int wg = row >> 6, n = row & 63;
    int b = wg >> 6, wi = wg & 63;
    int hp = ((wi >> 3) << 3) + (n >> 3);
    int wp = ((wi & 7) << 3) + (n & 7);
    int h = (hp + 4) & 63, w = (wp + 4) & 63;   // roll(-4): rolled[i] = x[(i+4)%64]
    src = ((size_t)b * 4096 + h * 64 + w) * DIM;
  } else {
    src = (size_t)row * DIM;
  }
  float v = x[src + c];
  float s = v, ss = v * v;
  #pragma unroll
  for (int off = 32; off; off >>= 1) {
    s  += __shfl_xor(s,  off, 64);
    ss += __shfl_xor(ss, off, 64);
  }
  __shared__ float red[12];
  const int wave = threadIdx.x >> 6, lane = threadIdx.x & 63;
  if (lane == 0) { red[wave] = s; red[6 + wave] = ss; }
  __syncthreads();
  if (threadIdx.x == 0) {
    float ts = 0.f, tss = 0.f;
    #pragma unroll
    for (int i = 0; i < 6; i++) { ts += red[i]; tss += red[6 + i]; }
    red[0] = ts; red[6] = tss;
  }
  __syncthreads();
  const float mean = red[0] * (1.0f / DIM);
  const float var  = red[6] * (1.0f / DIM) - mean * mean;
  const float inv  = rsqrtf(var + 1e-5f);
  out[(size_t)row * DIM + c] = __float2bfloat16((v - mean) * inv * g[c] + bta[c]);
}

// ---------------- GEMM: C = A(MxK) * Bt(NxK)^T, bf16 MFMA 16x16x32 ---------------
// 128x128 tile, BK=64, 4 waves (each 64x64).
// R6: 2-PHASE DOUBLE-BUFFERED pipeline (T3-minimum recipe). R4/R5 counters
// (MFMA 17 / VALU ~25 per-SIMD / HBM 15 / occ ~21%, zero bank conflicts) showed
// the 1-phase loop was drain-bound: with only 6 K-steps at K=384 and ~2 resident
// blocks/CU, every step exposed the full global->LDS latency at the pre-compute
// barrier. Now: prologue stages tile 0; each iter issues GLDS for tile t+1 into
// buf^1 BEFORE computing tile t from buf, single __syncthreads() per iter at the
// end (its vmcnt(0) drain sits AFTER ~400cy of ds_read+MFMA -> latency hidden).
// LDS 32->64 KB (2 blocks/CU static, == measured resident occupancy anyway).
// Row stride 128 B => chunk slot s occupies banks 4s..4s+3 in every row, so
// chunk-XOR swizzle by row: slot = g ^ (R&7) on store, read slot (hh*4+q)^(r&7)
// -> 2-way conflicts = free. Staging: 4 GLDS16 x 8 rows x 128 B per operand.
// XCD-aware 1-D grid remap: all gridN N-blocks of one M-block land consecutive
// on ONE XCD -> A tile fetched once into that XCD's L2 (R4: FETCH 355->157 MB).
// EPI: 0 = +bias -> bf16 out
//      1 = +bias, fast GELU (tanh-form via sigmoid+v_exp) -> bf16 out
//          (R5: erff->fast gelu was NEUTRAL: epilogue VALU was not the limit)
//      2 = +bias, window-reverse+roll scatter, + residual x -> f32 out
//      3 = +bias, += into f32 out (row-major)
template <int EPI>
__global__ __launch_bounds__(256) void gemm_bt(
    const bf16* __restrict__ A, const bf16* __restrict__ Bt,
    const float* __restrict__ bias,
    bf16* __restrict__ outb, float* __restrict__ outf,
    const float* __restrict__ resid,
    int M, int N, int K, int gridN)
{
  __shared__ bf16 As[2][128 * 64];   // 16 KB per buffer per operand
  __shared__ bf16 Bs[2][128 * 64];
  const int tid = threadIdx.x;
  const int wave = tid >> 6, lane = tid & 63;

  // XCD-aware remap (gridM = M/128 divisible by 8)
  const int bid = blockIdx.x;
  const int xcd = bid & 7, slot = bid >> 3;
  const int n_blk = slot % gridN;
  const int m_blk = (slot / gridN) * 8 + xcd;
  const int m0 = m_blk * 128, n0 = n_blk * 128;

  f32x4 acc[4][4];
  #pragma unroll
  for (int i = 0; i < 4; i++)
    #pragma unroll
    for (int j = 0; j < 4; j++) acc[i][j] = (f32x4){0.f, 0.f, 0.f, 0.f};

  const int q = lane >> 4, r = lane & 15;
  const int mwav = (wave >> 1) * 64, nwav = (wave & 1) * 64;

  // staging: wave covers rows [wave*32, wave*32+32) of A and B, 4 insts each of
  // 8 rows x 128 B. lane l -> dest row +(l>>3), chunk slot l&7.
  // source chunk g = (l&7) ^ (R&7), R&7 = (l>>3)&7 (bases are multiples of 8).
  const int srow = wave * 32 + (lane >> 3);
  const int gchunk = (lane & 7) ^ ((lane >> 3) & 7);
  const char* Ac = (const char*)A + (size_t)(m0 + srow) * K * 2 + gchunk * 16;
  const char* Bc = (const char*)Bt + (size_t)(n0 + srow) * K * 2 + gchunk * 16;
  const size_t rowskip8 = (size_t)8 * K * 2;
  const int ldsbase = wave * 32 * 64;   // element index of this wave's region

  const int rxor = r & 7;
  const int nt = K >> 6;                // number of BK=64 tiles (6 or 24)

  // prologue: stage tile 0 into buffer 0, full drain once
  {
    bf16* Ad = &As[0][ldsbase];
    bf16* Bd = &Bs[0][ldsbase];
    GLDS16(Ac,                Ad +  0 * 64);
    GLDS16(Ac + rowskip8,     Ad +  8 * 64);
    GLDS16(Ac + 2 * rowskip8, Ad + 16 * 64);
    GLDS16(Ac + 3 * rowskip8, Ad + 24 * 64);
    GLDS16(Bc,                Bd +  0 * 64);
    GLDS16(Bc + rowskip8,     Bd +  8 * 64);
    GLDS16(Bc + 2 * rowskip8, Bd + 16 * 64);
    GLDS16(Bc + 3 * rowskip8, Bd + 24 * 64);
  }
  __syncthreads();

  int cur = 0;
  for (int t = 0; t < nt; ++t) {
    // issue prefetch of tile t+1 into the other buffer (no wait here)
    if (t + 1 < nt) {
      const size_t kb = (size_t)(t + 1) * 128;   // 64 elems * 2 B
      bf16* Ad = &As[cur ^ 1][ldsbase];
      bf16* Bd = &Bs[cur ^ 1][ldsbase];
      GLDS16(Ac + kb,                Ad +  0 * 64);
      GLDS16(Ac + kb + rowskip8,     Ad +  8 * 64);
      GLDS16(Ac + kb + 2 * rowskip8, Ad + 16 * 64);
      GLDS16(Ac + kb + 3 * rowskip8, Ad + 24 * 64);
      GLDS16(Bc + kb,                Bd +  0 * 64);
      GLDS16(Bc + kb + rowskip8,     Bd +  8 * 64);
      GLDS16(Bc + kb + 2 * rowskip8, Bd + 16 * 64);
      GLDS16(Bc + kb + 3 * rowskip8, Bd + 24 * 64);
    }

    // compute tile t from buf[cur] (ready: drained by barrier of prev iter)
    const bf16* Ar = As[cur];
    const bf16* Br = Bs[cur];
    #pragma unroll
    for (int hh = 0; hh < 2; hh++) {
      const int s = (hh * 4 + q) ^ rxor;
      bf16x8 af[4], bfr[4];
      #pragma unroll
      for (int mi = 0; mi < 4; mi++)
        af[mi] = *(const bf16x8*)(&Ar[(mwav + mi * 16 + r) * 64 + s * 8]);
      #pragma unroll
      for (int ni = 0; ni < 4; ni++)
        bfr[ni] = *(const bf16x8*)(&Br[(nwav + ni * 16 + r) * 64 + s * 8]);
      #pragma unroll
      for (int mi = 0; mi < 4; mi++)
        #pragma unroll
        for (int ni = 0; ni < 4; ni++)
          acc[mi][ni] = __builtin_amdgcn_mfma_f32_16x16x32_bf16(af[mi], bfr[ni], acc[mi][ni], 0, 0, 0);
    }

    // single barrier per K-step: drains this iter's prefetch (vmcnt(0)) AFTER
    // compute ran, and fences buf reuse across waves.
    __syncthreads();
    cur ^= 1;
  }

  // epilogue: D row = (lane>>4)*4 + reg (M), col = lane&15 (N)  [m89-verified]
  #pragma unroll
  for (int mi = 0; mi < 4; mi++) {
    #pragma unroll
    for (int ni = 0; ni < 4; ni++) {
      #pragma unroll
      for (int rr = 0; rr < 4; rr++) {
        const int row = m0 + mwav + mi * 16 + q * 4 + rr;
        const int col = n0 + nwav + ni * 16 + r;
        float val = acc[mi][ni][rr] + bias[col];
        if (EPI == 0) {
          outb[(size_t)row * N + col] = __float2bfloat16(val);
        } else if (EPI == 1) {
          // gelu(x) ~= x * sigmoid(1.5957691x + 0.0713548x^3)  (tanh-form)
          const float t = val * val;
          const float z = val * fmaf(t, 0.07135481283f, 1.5957691216f);
          const float gl = val / (1.0f + __expf(-z));
          outb[(size_t)row * N + col] = __float2bfloat16(gl);
        } else if (EPI == 2) {
          const int wg = row >> 6, n = row & 63;
          const int b = wg >> 6, wi = wg & 63;
          const int hp = ((wi >> 3) << 3) + (n >> 3);
          const int wp = ((wi & 7) << 3) + (n & 7);
          const int h = (hp + 4) & 63, w = (wp + 4) & 63;  // roll(+4): final[(i+4)%64]=tmp[i]
          const size_t dst = ((size_t)b * 4096 + h * 64 + w) * DIM + col;
          outf[dst] = resid[dst] + val;
        } else {
          outf[(size_t)row * N + col] += val;
        }
      }
    }
  }
}

// ---------------- K3: windowed attention, one block per (window, head) -----------
__device__ __forceinline__ int regid(int v) { return v < 56 ? 0 : (v < 60 ? 1 : 2); }

__global__ __launch_bounds__(256) void attn_kernel(
    const bf16* __restrict__ qkv, const float* __restrict__ tau,
    const float* __restrict__ rpb, bf16* __restrict__ outb)
{
  const int h = blockIdx.x;          // head
  const int w = blockIdx.y;          // global window (b*64 + wy*8 + wx)
  const int t = threadIdx.x;
  const int row = t >> 2, seg = t & 3;

  __shared__ float qs[64][36];
  __shared__ float ks[64][36];
  __shared__ float vs[64][36];
  __shared__ float rpb_s[225];

  // load q/k/v (8 dims per thread), fused l2norm + tau scale
  const size_t base = ((size_t)w * 64 + row) * 1152 + h * 32 + seg * 8;
  float qf[8], kf[8], vf[8];
  {
    uint4 uq = *(const uint4*)(qkv + base);
    uint4 uk = *(const uint4*)(qkv + base + 384);
    uint4 uv = *(const uint4*)(qkv + base + 768);
    const bf16* pq = (const bf16*)&uq;
    const bf16* pk = (const bf16*)&uk;
    const bf16* pv = (const bf16*)&uv;
    #pragma unroll
    for (int i = 0; i < 8; i++) {
      qf[i] = __bfloat162float(pq[i]);
      kf[i] = __bfloat162float(pk[i]);
      vf[i] = __bfloat162float(pv[i]);
    }
  }
  float ssq = 0.f, ssk = 0.f;
  #pragma unroll
  for (int i = 0; i < 8; i++) { ssq += qf[i] * qf[i]; ssk += kf[i] * kf[i]; }
  ssq += __shfl_xor(ssq, 1, 64); ssq += __shfl_xor(ssq, 2, 64);
  ssk += __shfl_xor(ssk, 1, 64); ssk += __shfl_xor(ssk, 2, 64);
  const float qsc = (1.0f / fmaxf(sqrtf(ssq), 1e-12f)) * (1.0f / fmaxf(tau[h], 1e-3f));
  const float ksc = 1.0f / fmaxf(sqrtf(ssk), 1e-12f);
  #pragma unroll
  for (int i = 0; i < 8; i++) {
    qs[row][seg * 8 + i] = qf[i] * qsc;
    ks[row][seg * 8 + i] = kf[i] * ksc;
    vs[row][seg * 8 + i] = vf[i];
  }
  if (t < 225) rpb_s[t] = rpb[t * NHEADS + h];
  __syncthreads();

  float4 qr[8];
  #pragma unroll
  for (int u = 0; u < 8; u++) qr[u] = *(const float4*)&qs[row][u * 4];

  const int wi = w & 63;
  const int wy = wi >> 3, wx = wi & 7;
  const int iy = row >> 3, ix = row & 7;
  const int reg_i = regid(wy * 8 + iy) * 3 + regid(wx * 8 + ix);

  // scores for this row, j = jj*4 + seg (bank-conflict-free interleave)
  float sv[16];
  float mx = -3e38f;
  #pragma unroll
  for (int jj = 0; jj < 16; jj++) {
    const int j = jj * 4 + seg;
    const float4* kr = (const float4*)&ks[j][0];
    float dot = 0.f;
    #pragma unroll
    for (int u = 0; u < 8; u++) {
      float4 kk = kr[u];
      dot += qr[u].x * kk.x; dot += qr[u].y * kk.y;
      dot += qr[u].z * kk.z; dot += qr[u].w * kk.w;
    }
    const int jy = j >> 3, jx = j & 7;
    dot += rpb_s[(iy - jy + 7) * 15 + (ix - jx + 7)];
    const int reg_j = regid(wy * 8 + jy) * 3 + regid(wx * 8 + jx);
    if (reg_j != reg_i) dot -= 1e9f;
    sv[jj] = dot;
    mx = fmaxf(mx, dot);
  }
  mx = fmaxf(mx, __shfl_xor(mx, 1, 64));
  mx = fmaxf(mx, __shfl_xor(mx, 2, 64));
  float sum = 0.f;
  #pragma unroll
  for (int jj = 0; jj < 16; jj++) { sv[jj] = __expf(sv[jj] - mx); sum += sv[jj]; }
  sum += __shfl_xor(sum, 1, 64); sum += __shfl_xor(sum, 2, 64);
  const float rinv = 1.0f / sum;

  float4 po[8];
  #pragma unroll
  for (int u = 0; u < 8; u++) po[u] = make_float4(0.f, 0.f, 0.f, 0.f);
  #pragma unroll
  for (int jj = 0; jj < 16; jj++) {
    const float p = sv[jj] * rinv;
    const float4* vr = (const float4*)&vs[jj * 4 + seg][0];
    #pragma unroll
    for (int u = 0; u < 8; u++) {
      float4 vv = vr[u];
      po[u].x += p * vv.x; po[u].y += p * vv.y;
      po[u].z += p * vv.z; po[u].w += p * vv.w;
    }
  }
  #pragma unroll
  for (int u = 0; u < 8; u++) {
    po[u].x += __shfl_xor(po[u].x, 1, 64); po[u].x += __shfl_xor(po[u].x, 2, 64);
    po[u].y += __shfl_xor(po[u].y, 1, 64); po[u].y += __shfl_xor(po[u].y, 2, 64);
    po[u].z += __shfl_xor(po[u].z, 1, 64); po[u].z += __shfl_xor(po[u].z, 2, 64);
    po[u].w += __shfl_xor(po[u].w, 1, 64); po[u].w += __shfl_xor(po[u].w, 2, 64);
  }
  // each thread writes its 8 dims: float4 indices seg*2, seg*2+1 (static select)
  float4 o0, o1;
  switch (seg) {
    case 0: o0 = po[0]; o1 = po[1]; break;
    case 1: o0 = po[2]; o1 = po[3]; break;
    case 2: o0 = po[4]; o1 = po[5]; break;
    default: o0 = po[6]; o1 = po[7]; break;
  }
  union { uint4 u; bf16 b[8]; } ou;
  ou.b[0] = __float2bfloat16(o0.x); ou.b[1] = __float2bfloat16(o0.y);
  ou.b[2] = __float2bfloat16(o0.z); ou.b[3] = __float2bfloat16(o0.w);
  ou.b[4] = __float2bfloat16(o1.x); ou.b[5] = __float2bfloat16(o1.y);
  ou.b[6] = __float2bfloat16(o1.z); ou.b[7] = __float2bfloat16(o1.w);
  *(uint4*)(outb + ((size_t)w * 64 + row) * DIM + h * 32 + seg * 8) = ou.u;
}

// ---------------- host launch ----------------
extern "C" void kernel_launch(void* const* d_in, const int* in_sizes, int n_in,
                              void* d_out, int out_size, void* d_ws, size_t ws_size,
                              hipStream_t stream) {
  const float* x      = (const float*)d_in[0];
  const float* ln1_g  = (const float*)d_in[3];
  const float* ln1_b  = (const float*)d_in[4];
  const float* qkv_w  = (const float*)d_in[5];
  const float* qkv_b  = (const float*)d_in[6];
  const float* proj_w = (const float*)d_in[7];
  const float* proj_b = (const float*)d_in[8];
  const float* tau    = (const float*)d_in[9];
  const float* rpb    = (const float*)d_in[10];
  const float* ln2_g  = (const float*)d_in[11];
  const float* ln2_b  = (const float*)d_in[12];
  const float* fc1_w  = (const float*)d_in[13];
  const float* fc1_b  = (const float*)d_in[14];
  const float* fc2_w  = (const float*)d_in[15];
  const float* fc2_b  = (const float*)d_in[16];
  float* out = (float*)d_out;
  char* ws = (char*)d_ws;

  // workspace layout (peak ~244 MiB, buffers reused)
  bf16* wT_qkv  = (bf16*)(ws + 0);            //  884,736 B (1152x384)
  bf16* wT_proj = (bf16*)(ws + 884736);       //  294,912 B (384x384)
  bf16* wT_fc1  = (bf16*)(ws + 1179648);      // 1,179,648 B (1536x384)
  bf16* wT_fc2  = (bf16*)(ws + 2359296);      // 1,179,648 B (384x1536)
  bf16* winb    = (bf16*)(ws + 4194304);      // 50,331,648 B (65536x384)
  bf16* qkvb    = (bf16*)(ws + 54525952);     // 150,994,944 B (65536x1152)
  bf16* attnb   = (bf16*)(ws + 205520896);    // 50,331,648 B (65536x384)
  bf16* xn2b    = winb;                        // reuse (win dead after qkv GEMM)
  bf16* hb      = qkvb;                        // reuse (qkv+attn dead) 201,326,592 B

  // K0: weight conversion+transpose
  wconv_kernel<<<(384 * 1152 + 255) / 256, 256, 0, stream>>>(qkv_w, wT_qkv, 384, 1152);
  wconv_kernel<<<(384 * 384 + 255) / 256, 256, 0, stream>>>(proj_w, wT_proj, 384, 384);
  wconv_kernel<<<(384 * 1536 + 255) / 256, 256, 0, stream>>>(fc1_w, wT_fc1, 384, 1536);
  wconv_kernel<<<(1536 * 384 + 255) / 256, 256, 0, stream>>>(fc2_w, wT_fc2, 1536, 384);

  // K1: LN1 + roll + window partition
  ln_kernel<<<MTOT, 384, 0, stream>>>(x, ln1_g, ln1_b, winb, 1);
  // K2: qkv GEMM (65536 x 1152 x 384), gridN = 9
  gemm_bt<0><<<(MTOT / 128) * (1152 / 128), 256, 0, stream>>>(
      winb, wT_qkv, qkv_b, qkvb, nullptr, nullptr, MTOT, 1152, 384, 1152 / 128);
  // K3: attention
  attn_kernel<<<dim3(NHEADS, 1024), 256, 0, stream>>>(qkvb, tau, rpb, attnb);
  // K4: proj GEMM + window-reverse/roll scatter + residual -> d_out, gridN = 3
  gemm_bt<2><<<(MTOT / 128) * (384 / 128), 256, 0, stream>>>(
      attnb, wT_proj, proj_b, nullptr, out, x, MTOT, 384, 384, 384 / 128);
  // K5: LN2
  ln_kernel<<<MTOT, 384, 0, stream>>>(out, ln2_g, ln2_b, xn2b, 0);
  // K6: fc1 + GELU, gridN = 12
  gemm_bt<1><<<(MTOT / 128) * (HID / 128), 256, 0, stream>>>(
      xn2b, wT_fc1, fc1_b, hb, nullptr, nullptr, MTOT, HID, 384, HID / 128);
  // K7: fc2 += into d_out, gridN = 3
  gemm_bt<3><<<(MTOT / 128) * (384 / 128), 256, 0, stream>>>(
      hb, wT_fc2, fc2_b, nullptr, out, nullptr, MTOT, 384, HID, 384 / 128);
}

// Round 4
// 935.895 us; speedup vs baseline: 1.0548x; 1.0548x over previous
//
#include <hip/hip_runtime.h>
#include <hip/hip_bf16.h>
#include <cstdint>

// ---------------- constants ----------------
#define DIM     384
#define NHEADS  12
#define HD      32
#define HGRID   64          // H = W = 64
#define NTOK    64          // tokens per 8x8 window
#define MTOT    65536       // 16 * 4096 rows
#define HID     1536

typedef __attribute__((ext_vector_type(8))) short bf16x8;
typedef __attribute__((ext_vector_type(4))) float f32x4;
typedef __hip_bfloat16 bf16;

typedef __attribute__((address_space(1))) const void* as1_cvp;
typedef __attribute__((address_space(3))) void*       as3_vp;
#define GLDS16(g, l) __builtin_amdgcn_global_load_lds((as1_cvp)(g), (as3_vp)(l), 16, 0, 0)

// ---------------- K0: weight fp32 (KxN) -> bf16 transposed (NxK) ----------------
__global__ void wconv_kernel(const float* __restrict__ src, bf16* __restrict__ dst,
                             int K, int N) {
  int i = blockIdx.x * 256 + threadIdx.x;
  if (i >= K * N) return;
  int n = i / K, k = i - n * K;
  dst[i] = __float2bfloat16(src[(size_t)k * N + n]);
}

// ---------------- K1/K5: LayerNorm (optionally fused roll+window gather) ----------
// blockIdx.x = OUTPUT row; 384 threads = one per channel.
__global__ __launch_bounds__(384) void ln_kernel(const float* __restrict__ x,
    const float* __restrict__ g, const float* __restrict__ bta,
    bf16* __restrict__ out, int windowed) {
  const int row = blockIdx.x;
  const int c = threadIdx.x;
  size_t src;
  if (windowed) {
    int wg = row >> 6, n = row & 63;
    int b = wg >> 6, wi = wg & 63;
    int hp = ((wi >> 3) << 3) + (n >> 3);
    int wp = ((wi & 7) << 3) + (n & 7);
    int h = (hp + 4) & 63, w = (wp + 4) & 63;   // roll(-4): rolled[i] = x[(i+4)%64]
    src = ((size_t)b * 4096 + h * 64 + w) * DIM;
  } else {
    src = (size_t)row * DIM;
  }
  float v = x[src + c];
  float s = v, ss = v * v;
  #pragma unroll
  for (int off = 32; off; off >>= 1) {
    s  += __shfl_xor(s,  off, 64);
    ss += __shfl_xor(ss, off, 64);
  }
  __shared__ float red[12];
  const int wave = threadIdx.x >> 6, lane = threadIdx.x & 63;
  if (lane == 0) { red[wave] = s; red[6 + wave] = ss; }
  __syncthreads();
  if (threadIdx.x == 0) {
    float ts = 0.f, tss = 0.f;
    #pragma unroll
    for (int i = 0; i < 6; i++) { ts += red[i]; tss += red[6 + i]; }
    red[0] = ts; red[6] = tss;
  }
  __syncthreads();
  const float mean = red[0] * (1.0f / DIM);
  const float var  = red[6] * (1.0f / DIM) - mean * mean;
  const float inv  = rsqrtf(var + 1e-5f);
  out[(size_t)row * DIM + c] = __float2bfloat16((v - mean) * inv * g[c] + bta[c]);
}

// ---------------- GEMM: C = A(MxK) * Bt(NxK)^T, bf16 MFMA 16x16x32 ---------------
// 128x128 tile, BK=64, double-buffered 2-phase pipeline.
// R7: 512 THREADS / 8 WAVES (2M x 4N wave grid, each wave 64x32 output).
// R3 counters (MFMA 15.6 / VALU 11 / HBM 16.6 / occ 21%, zero conflicts) showed
// pure latency-bound: 256 thr + 64 KB LDS = 2 blk/CU x 4 waves = 2 waves/SIMD --
// not enough TLP to hide ~900cy HBM latency (K=384 -> only 6 steps) nor the
// scattered f32 RMW epilogues (proj/fc2). 512 thr keeps 2 blk/CU (LDS 64 KB x2
// = 128 <= 160) -> 16 waves/CU = 4 waves/SIMD; acc halves to 8 f32x4 (VGPR
// under the 128 boundary); epilogue per-thread work halves; staging 4 GLDS16.
// Row stride 128 B => chunk slot s occupies banks 4s..4s+3 in every row, so
// chunk-XOR swizzle by row: slot = g ^ (R&7) on store, read slot (hh*4+q)^(r&7)
// -> 2-way conflicts = free.
// XCD-aware 1-D grid remap: all gridN N-blocks of one M-block land consecutive
// on ONE XCD -> A tile fetched once into that XCD's L2 (R4: FETCH 355->157 MB).
// EPI: 0 = +bias -> bf16 out
//      1 = +bias, fast GELU (tanh-form via sigmoid+v_exp) -> bf16 out
//      2 = +bias, window-reverse+roll scatter, + residual x -> f32 out
//      3 = +bias, += into f32 out (row-major)
template <int EPI>
__global__ __launch_bounds__(512) void gemm_bt(
    const bf16* __restrict__ A, const bf16* __restrict__ Bt,
    const float* __restrict__ bias,
    bf16* __restrict__ outb, float* __restrict__ outf,
    const float* __restrict__ resid,
    int M, int N, int K, int gridN)
{
  __shared__ bf16 As[2][128 * 64];   // 16 KB per buffer per operand
  __shared__ bf16 Bs[2][128 * 64];
  const int tid = threadIdx.x;
  const int wave = tid >> 6, lane = tid & 63;

  // XCD-aware remap (gridM = M/128 divisible by 8)
  const int bid = blockIdx.x;
  const int xcd = bid & 7, slot = bid >> 3;
  const int n_blk = slot % gridN;
  const int m_blk = (slot / gridN) * 8 + xcd;
  const int m0 = m_blk * 128, n0 = n_blk * 128;

  f32x4 acc[4][2];
  #pragma unroll
  for (int i = 0; i < 4; i++)
    #pragma unroll
    for (int j = 0; j < 2; j++) acc[i][j] = (f32x4){0.f, 0.f, 0.f, 0.f};

  const int q = lane >> 4, r = lane & 15;
  const int mwav = (wave >> 2) * 64;   // 2 M-halves
  const int nwav = (wave & 3) * 32;    // 4 N-quarters

  // staging: wave w covers rows [w*16, w*16+16) of A and of B; 2 GLDS16 each
  // (8 rows x 128 B per inst). lane l -> dest row +(l>>3), chunk slot l&7.
  // source chunk g = (l&7) ^ (R&7); R&7 = (l>>3)&7 for both insts (row bases
  // w*16 and w*16+8 are multiples of 8).
  const int srow = wave * 16 + (lane >> 3);
  const int gchunk = (lane & 7) ^ ((lane >> 3) & 7);
  const char* Ac = (const char*)A + (size_t)(m0 + srow) * K * 2 + gchunk * 16;
  const char* Bc = (const char*)Bt + (size_t)(n0 + srow) * K * 2 + gchunk * 16;
  const size_t rowskip8 = (size_t)8 * K * 2;
  const int ldsbase = wave * 16 * 64;   // element index of this wave's region

  const int rxor = r & 7;
  const int nt = K >> 6;                // number of BK=64 tiles (6 or 24)

  // prologue: stage tile 0 into buffer 0
  {
    bf16* Ad = &As[0][ldsbase];
    bf16* Bd = &Bs[0][ldsbase];
    GLDS16(Ac,            Ad + 0 * 64);
    GLDS16(Ac + rowskip8, Ad + 8 * 64);
    GLDS16(Bc,            Bd + 0 * 64);
    GLDS16(Bc + rowskip8, Bd + 8 * 64);
  }
  __syncthreads();

  int cur = 0;
  for (int t = 0; t < nt; ++t) {
    // issue prefetch of tile t+1 into the other buffer (no wait here)
    if (t + 1 < nt) {
      const size_t kb = (size_t)(t + 1) * 128;   // 64 elems * 2 B
      bf16* Ad = &As[cur ^ 1][ldsbase];
      bf16* Bd = &Bs[cur ^ 1][ldsbase];
      GLDS16(Ac + kb,            Ad + 0 * 64);
      GLDS16(Ac + kb + rowskip8, Ad + 8 * 64);
      GLDS16(Bc + kb,            Bd + 0 * 64);
      GLDS16(Bc + kb + rowskip8, Bd + 8 * 64);
    }

    // compute tile t from buf[cur] (ready: drained by barrier of prev iter)
    const bf16* Ar = As[cur];
    const bf16* Br = Bs[cur];
    #pragma unroll
    for (int hh = 0; hh < 2; hh++) {
      const int s = (hh * 4 + q) ^ rxor;
      bf16x8 af[4], bfr[2];
      #pragma unroll
      for (int mi = 0; mi < 4; mi++)
        af[mi] = *(const bf16x8*)(&Ar[(mwav + mi * 16 + r) * 64 + s * 8]);
      #pragma unroll
      for (int ni = 0; ni < 2; ni++)
        bfr[ni] = *(const bf16x8*)(&Br[(nwav + ni * 16 + r) * 64 + s * 8]);
      #pragma unroll
      for (int mi = 0; mi < 4; mi++)
        #pragma unroll
        for (int ni = 0; ni < 2; ni++)
          acc[mi][ni] = __builtin_amdgcn_mfma_f32_16x16x32_bf16(af[mi], bfr[ni], acc[mi][ni], 0, 0, 0);
    }

    // single barrier per K-step: drains this iter's prefetch (vmcnt(0)) AFTER
    // compute ran, and fences buf reuse across waves.
    __syncthreads();
    cur ^= 1;
  }

  // epilogue: D row = (lane>>4)*4 + reg (M), col = lane&15 (N)  [m89-verified]
  #pragma unroll
  for (int mi = 0; mi < 4; mi++) {
    #pragma unroll
    for (int ni = 0; ni < 2; ni++) {
      #pragma unroll
      for (int rr = 0; rr < 4; rr++) {
        const int row = m0 + mwav + mi * 16 + q * 4 + rr;
        const int col = n0 + nwav + ni * 16 + r;
        float val = acc[mi][ni][rr] + bias[col];
        if (EPI == 0) {
          outb[(size_t)row * N + col] = __float2bfloat16(val);
        } else if (EPI == 1) {
          // gelu(x) ~= x * sigmoid(1.5957691x + 0.0713548x^3)  (tanh-form)
          const float t = val * val;
          const float z = val * fmaf(t, 0.07135481283f, 1.5957691216f);
          const float gl = val / (1.0f + __expf(-z));
          outb[(size_t)row * N + col] = __float2bfloat16(gl);
        } else if (EPI == 2) {
          const int wg = row >> 6, n = row & 63;
          const int b = wg >> 6, wi = wg & 63;
          const int hp = ((wi >> 3) << 3) + (n >> 3);
          const int wp = ((wi & 7) << 3) + (n & 7);
          const int h = (hp + 4) & 63, w = (wp + 4) & 63;  // roll(+4): final[(i+4)%64]=tmp[i]
          const size_t dst = ((size_t)b * 4096 + h * 64 + w) * DIM + col;
          outf[dst] = resid[dst] + val;
        } else {
          outf[(size_t)row * N + col] += val;
        }
      }
    }
  }
}

// ---------------- K3: windowed attention, one block per (window, head) -----------
__device__ __forceinline__ int regid(int v) { return v < 56 ? 0 : (v < 60 ? 1 : 2); }

__global__ __launch_bounds__(256) void attn_kernel(
    const bf16* __restrict__ qkv, const float* __restrict__ tau,
    const float* __restrict__ rpb, bf16* __restrict__ outb)
{
  const int h = blockIdx.x;          // head
  const int w = blockIdx.y;          // global window (b*64 + wy*8 + wx)
  const int t = threadIdx.x;
  const int row = t >> 2, seg = t & 3;

  __shared__ float qs[64][36];
  __shared__ float ks[64][36];
  __shared__ float vs[64][36];
  __shared__ float rpb_s[225];

  // load q/k/v (8 dims per thread), fused l2norm + tau scale
  const size_t base = ((size_t)w * 64 + row) * 1152 + h * 32 + seg * 8;
  float qf[8], kf[8], vf[8];
  {
    uint4 uq = *(const uint4*)(qkv + base);
    uint4 uk = *(const uint4*)(qkv + base + 384);
    uint4 uv = *(const uint4*)(qkv + base + 768);
    const bf16* pq = (const bf16*)&uq;
    const bf16* pk = (const bf16*)&uk;
    const bf16* pv = (const bf16*)&uv;
    #pragma unroll
    for (int i = 0; i < 8; i++) {
      qf[i] = __bfloat162float(pq[i]);
      kf[i] = __bfloat162float(pk[i]);
      vf[i] = __bfloat162float(pv[i]);
    }
  }
  float ssq = 0.f, ssk = 0.f;
  #pragma unroll
  for (int i = 0; i < 8; i++) { ssq += qf[i] * qf[i]; ssk += kf[i] * kf[i]; }
  ssq += __shfl_xor(ssq, 1, 64); ssq += __shfl_xor(ssq, 2, 64);
  ssk += __shfl_xor(ssk, 1, 64); ssk += __shfl_xor(ssk, 2, 64);
  const float qsc = (1.0f / fmaxf(sqrtf(ssq), 1e-12f)) * (1.0f / fmaxf(tau[h], 1e-3f));
  const float ksc = 1.0f / fmaxf(sqrtf(ssk), 1e-12f);
  #pragma unroll
  for (int i = 0; i < 8; i++) {
    qs[row][seg * 8 + i] = qf[i] * qsc;
    ks[row][seg * 8 + i] = kf[i] * ksc;
    vs[row][seg * 8 + i] = vf[i];
  }
  if (t < 225) rpb_s[t] = rpb[t * NHEADS + h];
  __syncthreads();

  float4 qr[8];
  #pragma unroll
  for (int u = 0; u < 8; u++) qr[u] = *(const float4*)&qs[row][u * 4];

  const int wi = w & 63;
  const int wy = wi >> 3, wx = wi & 7;
  const int iy = row >> 3, ix = row & 7;
  const int reg_i = regid(wy * 8 + iy) * 3 + regid(wx * 8 + ix);

  // scores for this row, j = jj*4 + seg (bank-conflict-free interleave)
  float sv[16];
  float mx = -3e38f;
  #pragma unroll
  for (int jj = 0; jj < 16; jj++) {
    const int j = jj * 4 + seg;
    const float4* kr = (const float4*)&ks[j][0];
    float dot = 0.f;
    #pragma unroll
    for (int u = 0; u < 8; u++) {
      float4 kk = kr[u];
      dot += qr[u].x * kk.x; dot += qr[u].y * kk.y;
      dot += qr[u].z * kk.z; dot += qr[u].w * kk.w;
    }
    const int jy = j >> 3, jx = j & 7;
    dot += rpb_s[(iy - jy + 7) * 15 + (ix - jx + 7)];
    const int reg_j = regid(wy * 8 + jy) * 3 + regid(wx * 8 + jx);
    if (reg_j != reg_i) dot -= 1e9f;
    sv[jj] = dot;
    mx = fmaxf(mx, dot);
  }
  mx = fmaxf(mx, __shfl_xor(mx, 1, 64));
  mx = fmaxf(mx, __shfl_xor(mx, 2, 64));
  float sum = 0.f;
  #pragma unroll
  for (int jj = 0; jj < 16; jj++) { sv[jj] = __expf(sv[jj] - mx); sum += sv[jj]; }
  sum += __shfl_xor(sum, 1, 64); sum += __shfl_xor(sum, 2, 64);
  const float rinv = 1.0f / sum;

  float4 po[8];
  #pragma unroll
  for (int u = 0; u < 8; u++) po[u] = make_float4(0.f, 0.f, 0.f, 0.f);
  #pragma unroll
  for (int jj = 0; jj < 16; jj++) {
    const float p = sv[jj] * rinv;
    const float4* vr = (const float4*)&vs[jj * 4 + seg][0];
    #pragma unroll
    for (int u = 0; u < 8; u++) {
      float4 vv = vr[u];
      po[u].x += p * vv.x; po[u].y += p * vv.y;
      po[u].z += p * vv.z; po[u].w += p * vv.w;
    }
  }
  #pragma unroll
  for (int u = 0; u < 8; u++) {
    po[u].x += __shfl_xor(po[u].x, 1, 64); po[u].x += __shfl_xor(po[u].x, 2, 64);
    po[u].y += __shfl_xor(po[u].y, 1, 64); po[u].y += __shfl_xor(po[u].y, 2, 64);
    po[u].z += __shfl_xor(po[u].z, 1, 64); po[u].z += __shfl_xor(po[u].z, 2, 64);
    po[u].w += __shfl_xor(po[u].w, 1, 64); po[u].w += __shfl_xor(po[u].w, 2, 64);
  }
  // each thread writes its 8 dims: float4 indices seg*2, seg*2+1 (static select)
  float4 o0, o1;
  switch (seg) {
    case 0: o0 = po[0]; o1 = po[1]; break;
    case 1: o0 = po[2]; o1 = po[3]; break;
    case 2: o0 = po[4]; o1 = po[5]; break;
    default: o0 = po[6]; o1 = po[7]; break;
  }
  union { uint4 u; bf16 b[8]; } ou;
  ou.b[0] = __float2bfloat16(o0.x); ou.b[1] = __float2bfloat16(o0.y);
  ou.b[2] = __float2bfloat16(o0.z); ou.b[3] = __float2bfloat16(o0.w);
  ou.b[4] = __float2bfloat16(o1.x); ou.b[5] = __float2bfloat16(o1.y);
  ou.b[6] = __float2bfloat16(o1.z); ou.b[7] = __float2bfloat16(o1.w);
  *(uint4*)(outb + ((size_t)w * 64 + row) * DIM + h * 32 + seg * 8) = ou.u;
}

// ---------------- host launch ----------------
extern "C" void kernel_launch(void* const* d_in, const int* in_sizes, int n_in,
                              void* d_out, int out_size, void* d_ws, size_t ws_size,
                              hipStream_t stream) {
  const float* x      = (const float*)d_in[0];
  const float* ln1_g  = (const float*)d_in[3];
  const float* ln1_b  = (const float*)d_in[4];
  const float* qkv_w  = (const float*)d_in[5];
  const float* qkv_b  = (const float*)d_in[6];
  const float* proj_w = (const float*)d_in[7];
  const float* proj_b = (const float*)d_in[8];
  const float* tau    = (const float*)d_in[9];
  const float* rpb    = (const float*)d_in[10];
  const float* ln2_g  = (const float*)d_in[11];
  const float* ln2_b  = (const float*)d_in[12];
  const float* fc1_w  = (const float*)d_in[13];
  const float* fc1_b  = (const float*)d_in[14];
  const float* fc2_w  = (const float*)d_in[15];
  const float* fc2_b  = (const float*)d_in[16];
  float* out = (float*)d_out;
  char* ws = (char*)d_ws;

  // workspace layout (peak ~244 MiB, buffers reused)
  bf16* wT_qkv  = (bf16*)(ws + 0);            //  884,736 B (1152x384)
  bf16* wT_proj = (bf16*)(ws + 884736);       //  294,912 B (384x384)
  bf16* wT_fc1  = (bf16*)(ws + 1179648);      // 1,179,648 B (1536x384)
  bf16* wT_fc2  = (bf16*)(ws + 2359296);      // 1,179,648 B (384x1536)
  bf16* winb    = (bf16*)(ws + 4194304);      // 50,331,648 B (65536x384)
  bf16* qkvb    = (bf16*)(ws + 54525952);     // 150,994,944 B (65536x1152)
  bf16* attnb   = (bf16*)(ws + 205520896);    // 50,331,648 B (65536x384)
  bf16* xn2b    = winb;                        // reuse (win dead after qkv GEMM)
  bf16* hb      = qkvb;                        // reuse (qkv+attn dead) 201,326,592 B

  // K0: weight conversion+transpose
  wconv_kernel<<<(384 * 1152 + 255) / 256, 256, 0, stream>>>(qkv_w, wT_qkv, 384, 1152);
  wconv_kernel<<<(384 * 384 + 255) / 256, 256, 0, stream>>>(proj_w, wT_proj, 384, 384);
  wconv_kernel<<<(384 * 1536 + 255) / 256, 256, 0, stream>>>(fc1_w, wT_fc1, 384, 1536);
  wconv_kernel<<<(1536 * 384 + 255) / 256, 256, 0, stream>>>(fc2_w, wT_fc2, 1536, 384);

  // K1: LN1 + roll + window partition
  ln_kernel<<<MTOT, 384, 0, stream>>>(x, ln1_g, ln1_b, winb, 1);
  // K2: qkv GEMM (65536 x 1152 x 384), gridN = 9
  gemm_bt<0><<<(MTOT / 128) * (1152 / 128), 512, 0, stream>>>(
      winb, wT_qkv, qkv_b, qkvb, nullptr, nullptr, MTOT, 1152, 384, 1152 / 128);
  // K3: attention
  attn_kernel<<<dim3(NHEADS, 1024), 256, 0, stream>>>(qkvb, tau, rpb, attnb);
  // K4: proj GEMM + window-reverse/roll scatter + residual -> d_out, gridN = 3
  gemm_bt<2><<<(MTOT / 128) * (384 / 128), 512, 0, stream>>>(
      attnb, wT_proj, proj_b, nullptr, out, x, MTOT, 384, 384, 384 / 128);
  // K5: LN2
  ln_kernel<<<MTOT, 384, 0, stream>>>(out, ln2_g, ln2_b, xn2b, 0);
  // K6: fc1 + GELU, gridN = 12
  gemm_bt<1><<<(MTOT / 128) * (HID / 128), 512, 0, stream>>>(
      xn2b, wT_fc1, fc1_b, hb, nullptr, nullptr, MTOT, HID, 384, HID / 128);
  // K7: fc2 += into d_out, gridN = 3
  gemm_bt<3><<<(MTOT / 128) * (384 / 128), 512, 0, stream>>>(
      hb, wT_fc2, fc2_b, nullptr, out, nullptr, MTOT, 384, HID, 384 / 128);
}

// Round 5
// 844.475 us; speedup vs baseline: 1.1689x; 1.1083x over previous
//
#include <hip/hip_runtime.h>
#include <hip/hip_bf16.h>
#include <cstdint>

// ---------------- constants ----------------
#define DIM     384
#define NHEADS  12
#define HD      32
#define HGRID   64          // H = W = 64
#define NTOK    64          // tokens per 8x8 window
#define MTOT    65536       // 16 * 4096 rows
#define HID     1536

typedef __attribute__((ext_vector_type(8))) short bf16x8;
typedef __attribute__((ext_vector_type(4))) float f32x4;
typedef __hip_bfloat16 bf16;

typedef __attribute__((address_space(1))) const void* as1_cvp;
typedef __attribute__((address_space(3))) void*       as3_vp;
#define GLDS16(g, l) __builtin_amdgcn_global_load_lds((as1_cvp)(g), (as3_vp)(l), 16, 0, 0)

__device__ __forceinline__ float bf2f(short s) {
  union { unsigned int u; float f; } x;
  x.u = ((unsigned int)(unsigned short)s) << 16;
  return x.f;
}
__device__ __forceinline__ unsigned int f2u(float f) {
  union { bf16 b; unsigned short s; } c;
  c.b = __float2bfloat16(f);
  return (unsigned int)c.s;
}

// ---------------- K0: weight fp32 (KxN) -> bf16 transposed (NxK) ----------------
__global__ void wconv_kernel(const float* __restrict__ src, bf16* __restrict__ dst,
                             int K, int N) {
  int i = blockIdx.x * 256 + threadIdx.x;
  if (i >= K * N) return;
  int n = i / K, k = i - n * K;
  dst[i] = __float2bfloat16(src[(size_t)k * N + n]);
}

// ---------------- K1/K5: LayerNorm (optionally fused roll+window gather) ----------
__global__ __launch_bounds__(384) void ln_kernel(const float* __restrict__ x,
    const float* __restrict__ g, const float* __restrict__ bta,
    bf16* __restrict__ out, int windowed) {
  const int row = blockIdx.x;
  const int c = threadIdx.x;
  size_t src;
  if (windowed) {
    int wg = row >> 6, n = row & 63;
    int b = wg >> 6, wi = wg & 63;
    int hp = ((wi >> 3) << 3) + (n >> 3);
    int wp = ((wi & 7) << 3) + (n & 7);
    int h = (hp + 4) & 63, w = (wp + 4) & 63;   // roll(-4): rolled[i] = x[(i+4)%64]
    src = ((size_t)b * 4096 + h * 64 + w) * DIM;
  } else {
    src = (size_t)row * DIM;
  }
  float v = x[src + c];
  float s = v, ss = v * v;
  #pragma unroll
  for (int off = 32; off; off >>= 1) {
    s  += __shfl_xor(s,  off, 64);
    ss += __shfl_xor(ss, off, 64);
  }
  __shared__ float red[12];
  const int wave = threadIdx.x >> 6, lane = threadIdx.x & 63;
  if (lane == 0) { red[wave] = s; red[6 + wave] = ss; }
  __syncthreads();
  if (threadIdx.x == 0) {
    float ts = 0.f, tss = 0.f;
    #pragma unroll
    for (int i = 0; i < 6; i++) { ts += red[i]; tss += red[6 + i]; }
    red[0] = ts; red[6] = tss;
  }
  __syncthreads();
  const float mean = red[0] * (1.0f / DIM);
  const float var  = red[6] * (1.0f / DIM) - mean * mean;
  const float inv  = rsqrtf(var + 1e-5f);
  out[(size_t)row * DIM + c] = __float2bfloat16((v - mean) * inv * g[c] + bta[c]);
}

// ---------------- GEMM: C = A(MxK) * Bt(NxK)^T, bf16 MFMA 16x16x32 ---------------
// (unchanged from R4: 512 thr / 8 waves, 128x128 tile, BK=64, 2-phase dbuf.)
template <int EPI>
__global__ __launch_bounds__(512) void gemm_bt(
    const bf16* __restrict__ A, const bf16* __restrict__ Bt,
    const float* __restrict__ bias,
    bf16* __restrict__ outb, float* __restrict__ outf,
    const float* __restrict__ resid,
    int M, int N, int K, int gridN)
{
  __shared__ bf16 As[2][128 * 64];
  __shared__ bf16 Bs[2][128 * 64];
  const int tid = threadIdx.x;
  const int wave = tid >> 6, lane = tid & 63;

  const int bid = blockIdx.x;
  const int xcd = bid & 7, slot = bid >> 3;
  const int n_blk = slot % gridN;
  const int m_blk = (slot / gridN) * 8 + xcd;
  const int m0 = m_blk * 128, n0 = n_blk * 128;

  f32x4 acc[4][2];
  #pragma unroll
  for (int i = 0; i < 4; i++)
    #pragma unroll
    for (int j = 0; j < 2; j++) acc[i][j] = (f32x4){0.f, 0.f, 0.f, 0.f};

  const int q = lane >> 4, r = lane & 15;
  const int mwav = (wave >> 2) * 64;
  const int nwav = (wave & 3) * 32;

  const int srow = wave * 16 + (lane >> 3);
  const int gchunk = (lane & 7) ^ ((lane >> 3) & 7);
  const char* Ac = (const char*)A + (size_t)(m0 + srow) * K * 2 + gchunk * 16;
  const char* Bc = (const char*)Bt + (size_t)(n0 + srow) * K * 2 + gchunk * 16;
  const size_t rowskip8 = (size_t)8 * K * 2;
  const int ldsbase = wave * 16 * 64;

  const int rxor = r & 7;
  const int nt = K >> 6;

  {
    bf16* Ad = &As[0][ldsbase];
    bf16* Bd = &Bs[0][ldsbase];
    GLDS16(Ac,            Ad + 0 * 64);
    GLDS16(Ac + rowskip8, Ad + 8 * 64);
    GLDS16(Bc,            Bd + 0 * 64);
    GLDS16(Bc + rowskip8, Bd + 8 * 64);
  }
  __syncthreads();

  int cur = 0;
  for (int t = 0; t < nt; ++t) {
    if (t + 1 < nt) {
      const size_t kb = (size_t)(t + 1) * 128;
      bf16* Ad = &As[cur ^ 1][ldsbase];
      bf16* Bd = &Bs[cur ^ 1][ldsbase];
      GLDS16(Ac + kb,            Ad + 0 * 64);
      GLDS16(Ac + kb + rowskip8, Ad + 8 * 64);
      GLDS16(Bc + kb,            Bd + 0 * 64);
      GLDS16(Bc + kb + rowskip8, Bd + 8 * 64);
    }

    const bf16* Ar = As[cur];
    const bf16* Br = Bs[cur];
    #pragma unroll
    for (int hh = 0; hh < 2; hh++) {
      const int s = (hh * 4 + q) ^ rxor;
      bf16x8 af[4], bfr[2];
      #pragma unroll
      for (int mi = 0; mi < 4; mi++)
        af[mi] = *(const bf16x8*)(&Ar[(mwav + mi * 16 + r) * 64 + s * 8]);
      #pragma unroll
      for (int ni = 0; ni < 2; ni++)
        bfr[ni] = *(const bf16x8*)(&Br[(nwav + ni * 16 + r) * 64 + s * 8]);
      #pragma unroll
      for (int mi = 0; mi < 4; mi++)
        #pragma unroll
        for (int ni = 0; ni < 2; ni++)
          acc[mi][ni] = __builtin_amdgcn_mfma_f32_16x16x32_bf16(af[mi], bfr[ni], acc[mi][ni], 0, 0, 0);
    }

    __syncthreads();
    cur ^= 1;
  }

  #pragma unroll
  for (int mi = 0; mi < 4; mi++) {
    #pragma unroll
    for (int ni = 0; ni < 2; ni++) {
      #pragma unroll
      for (int rr = 0; rr < 4; rr++) {
        const int row = m0 + mwav + mi * 16 + q * 4 + rr;
        const int col = n0 + nwav + ni * 16 + r;
        float val = acc[mi][ni][rr] + bias[col];
        if (EPI == 0) {
          outb[(size_t)row * N + col] = __float2bfloat16(val);
        } else if (EPI == 1) {
          const float t = val * val;
          const float z = val * fmaf(t, 0.07135481283f, 1.5957691216f);
          const float gl = val / (1.0f + __expf(-z));
          outb[(size_t)row * N + col] = __float2bfloat16(gl);
        } else if (EPI == 2) {
          const int wg = row >> 6, n = row & 63;
          const int b = wg >> 6, wi = wg & 63;
          const int hp = ((wi >> 3) << 3) + (n >> 3);
          const int wp = ((wi & 7) << 3) + (n & 7);
          const int h = (hp + 4) & 63, w = (wp + 4) & 63;
          const size_t dst = ((size_t)b * 4096 + h * 64 + w) * DIM + col;
          outf[dst] = resid[dst] + val;
        } else {
          outf[(size_t)row * N + col] += val;
        }
      }
    }
  }
}

// ---------------- K3: MFMA windowed attention, ONE WAVE per (window, head) -------
// R8 rewrite. R4 counters on the VALU attn (MfmaUtil 0, VALUBusy 67, HBM 15%)
// + arithmetic showed the LDS pipe as binder: 4 waves x 256 ds_read_b128 per
// (w,h) ~ 12k LDS-cycles. MFMA version: 96 LDS insts per (w,h), dot products on
// the matrix pipe.
//   S^T = mfma(K,Q)  -> lane holds S[i = mi*16+r][j = mj*16+q4*4+reg]
//   post-MFMA scaling: qsc (incl 1/tau) in-reg; ksc redistributed via LDS
//   softmax over j: 16 in-lane + shfl_xor(16,32)
//   P -> bf16 into chunk-XOR-swizzled LDS [i][j] (8B chunks, c^=r)
//   PV: A = P rows (ds_read_b64 x2), B = V^T frags scatter-gathered from
//   global (issued early, T14: latency hides under QK+softmax)
__device__ __forceinline__ int regid(int v) { return v < 56 ? 0 : (v < 60 ? 1 : 2); }

__global__ __launch_bounds__(256, 2) void attn_kernel(
    const bf16* __restrict__ qkv, const float* __restrict__ tau,
    const float* __restrict__ rpb, bf16* __restrict__ outb)
{
  const int wv = threadIdx.x >> 6;
  const int lane = threadIdx.x & 63;
  const int q4 = lane >> 4, r = lane & 15;
  const int h = blockIdx.x * 4 + wv;       // head
  const int w = blockIdx.y;                // global window

  __shared__ bf16  pbuf[4][64 * 64];       // 8 KB per wave, swizzled P
  __shared__ float rpb_s[4][228];
  __shared__ float kscs[4][64];

  // stage this head's rpb column (225 floats)
  for (int t = lane; t < 225; t += 64)
    rpb_s[wv][t] = rpb[t * NHEADS + h];

  // ---- Q/K fragments: lane holds row (mi*16+r), dims q4*8..+8 ----
  const size_t rowbase = ((size_t)w * 64) * 1152 + (size_t)h * 32;
  bf16x8 qf[4], kf[4];
  #pragma unroll
  for (int mi = 0; mi < 4; mi++) {
    const size_t ro = rowbase + (size_t)(mi * 16 + r) * 1152 + q4 * 8;
    qf[mi] = *(const bf16x8*)(qkv + ro);
    kf[mi] = *(const bf16x8*)(qkv + ro + 384);
  }

  // ---- V^T fragments: issue scatter loads EARLY (hide under QK+softmax) ----
  // vfrag[ks][nd] elem t = V[ks*32+q4*8+t][nd*16+r]
  const bf16* vbase = qkv + rowbase + 768;
  unsigned short vraw[2][2][8];
  #pragma unroll
  for (int ks = 0; ks < 2; ks++)
    #pragma unroll
    for (int nd = 0; nd < 2; nd++)
      #pragma unroll
      for (int t = 0; t < 8; t++)
        vraw[ks][nd][t] = *(const unsigned short*)(vbase +
            (size_t)(ks * 32 + q4 * 8 + t) * 1152 + nd * 16 + r);

  // ---- row norms (post-MFMA scaling; no operand re-rounding) ----
  float qsc[4];
  {
    const float tinv = 1.0f / fmaxf(tau[h], 1e-3f);
    #pragma unroll
    for (int mi = 0; mi < 4; mi++) {
      float sq = 0.f, sk = 0.f;
      #pragma unroll
      for (int e = 0; e < 8; e++) {
        float a = bf2f(qf[mi][e]), b = bf2f(kf[mi][e]);
        sq = fmaf(a, a, sq); sk = fmaf(b, b, sk);
      }
      sq += __shfl_xor(sq, 16, 64); sq += __shfl_xor(sq, 32, 64);
      sk += __shfl_xor(sk, 16, 64); sk += __shfl_xor(sk, 32, 64);
      qsc[mi] = tinv / fmaxf(sqrtf(sq), 1e-12f);
      if (q4 == 0) kscs[wv][mi * 16 + r] = 1.0f / fmaxf(sqrtf(sk), 1e-12f);
    }
  }

  // ---- S^T = K * Q^T : acc[mj][mi], rows j (from K), cols i (from Q) ----
  f32x4 sacc[4][4];
  #pragma unroll
  for (int a = 0; a < 4; a++)
    #pragma unroll
    for (int b = 0; b < 4; b++) sacc[a][b] = (f32x4){0.f, 0.f, 0.f, 0.f};
  #pragma unroll
  for (int mj = 0; mj < 4; mj++)
    #pragma unroll
    for (int mi = 0; mi < 4; mi++)
      sacc[mj][mi] = __builtin_amdgcn_mfma_f32_16x16x32_bf16(kf[mj], qf[mi], sacc[mj][mi], 0, 0, 0);

  // ---- geometry per lane ----
  const int wi = w & 63, wy = wi >> 3, wx = wi & 7;
  int byi[4], regi[4];
  #pragma unroll
  for (int mi = 0; mi < 4; mi++) {
    const int i = mi * 16 + r, iy = i >> 3, ix = i & 7;
    byi[mi]  = (iy + 7) * 15 + (ix + 7);
    regi[mi] = regid(wy * 8 + iy) * 3 + regid(wx * 8 + ix);
  }
  float kscv[4][4];
  #pragma unroll
  for (int mj = 0; mj < 4; mj++)
    #pragma unroll
    for (int reg = 0; reg < 4; reg++)
      kscv[mj][reg] = kscs[wv][mj * 16 + q4 * 4 + reg];

  // ---- scale + bias + mask, row-max ----
  float mx[4] = {-3e38f, -3e38f, -3e38f, -3e38f};
  #pragma unroll
  for (int mj = 0; mj < 4; mj++) {
    #pragma unroll
    for (int reg = 0; reg < 4; reg++) {
      const int j = mj * 16 + q4 * 4 + reg;
      const int jy = j >> 3, jx = j & 7;
      const int offj = jy * 15 + jx;
      const int regj = regid(wy * 8 + jy) * 3 + regid(wx * 8 + jx);
      const float kv = kscv[mj][reg];
      #pragma unroll
      for (int mi = 0; mi < 4; mi++) {
        float v = sacc[mj][mi][reg] * (qsc[mi] * kv) + rpb_s[wv][byi[mi] - offj];
        if (regj != regi[mi]) v -= 1e9f;
        sacc[mj][mi][reg] = v;
        mx[mi] = fmaxf(mx[mi], v);
      }
    }
  }
  float sum[4] = {0.f, 0.f, 0.f, 0.f};
  #pragma unroll
  for (int mi = 0; mi < 4; mi++) {
    mx[mi] = fmaxf(mx[mi], __shfl_xor(mx[mi], 16, 64));
    mx[mi] = fmaxf(mx[mi], __shfl_xor(mx[mi], 32, 64));
  }
  #pragma unroll
  for (int mj = 0; mj < 4; mj++)
    #pragma unroll
    for (int mi = 0; mi < 4; mi++)
      #pragma unroll
      for (int reg = 0; reg < 4; reg++) {
        float p = __expf(sacc[mj][mi][reg] - mx[mi]);
        sacc[mj][mi][reg] = p;
        sum[mi] += p;
      }
  float rinv[4];
  #pragma unroll
  for (int mi = 0; mi < 4; mi++) {
    sum[mi] += __shfl_xor(sum[mi], 16, 64);
    sum[mi] += __shfl_xor(sum[mi], 32, 64);
    rinv[mi] = 1.0f / sum[mi];
  }

  // ---- P -> bf16 -> swizzled LDS [i][j]; 8B chunk c = j>>2, store at c^r ----
  #pragma unroll
  for (int mj = 0; mj < 4; mj++) {
    #pragma unroll
    for (int mi = 0; mi < 4; mi++) {
      const int i = mi * 16 + r;
      const int cs = (mj * 4 + q4) ^ r;
      uint2 d;
      d.x = f2u(sacc[mj][mi][0] * rinv[mi]) | (f2u(sacc[mj][mi][1] * rinv[mi]) << 16);
      d.y = f2u(sacc[mj][mi][2] * rinv[mi]) | (f2u(sacc[mj][mi][3] * rinv[mi]) << 16);
      *(uint2*)(&pbuf[wv][i * 64 + cs * 4]) = d;
    }
  }

  // ---- pack V frags ----
  bf16x8 vf[2][2];
  #pragma unroll
  for (int ks = 0; ks < 2; ks++)
    #pragma unroll
    for (int nd = 0; nd < 2; nd++) {
      union { unsigned int u[4]; bf16x8 v; } t;
      #pragma unroll
      for (int e = 0; e < 4; e++)
        t.u[e] = (unsigned int)vraw[ks][nd][2 * e] |
                 ((unsigned int)vraw[ks][nd][2 * e + 1] << 16);
      vf[ks][nd] = t.v;
    }

  // ---- O = P * V ----
  f32x4 oacc[4][2];
  #pragma unroll
  for (int a = 0; a < 4; a++)
    #pragma unroll
    for (int b = 0; b < 2; b++) oacc[a][b] = (f32x4){0.f, 0.f, 0.f, 0.f};
  #pragma unroll
  for (int mi = 0; mi < 4; mi++) {
    const int i = mi * 16 + r;
    #pragma unroll
    for (int ks = 0; ks < 2; ks++) {
      const int c1 = (ks * 8 + q4 * 2) ^ r;
      const int c2 = (ks * 8 + q4 * 2 + 1) ^ r;
      union { unsigned int u[4]; bf16x8 v; } pf;
      uint2 lo = *(const uint2*)(&pbuf[wv][i * 64 + c1 * 4]);
      uint2 hi = *(const uint2*)(&pbuf[wv][i * 64 + c2 * 4]);
      pf.u[0] = lo.x; pf.u[1] = lo.y; pf.u[2] = hi.x; pf.u[3] = hi.y;
      #pragma unroll
      for (int nd = 0; nd < 2; nd++)
        oacc[mi][nd] = __builtin_amdgcn_mfma_f32_16x16x32_bf16(pf.v, vf[ks][nd], oacc[mi][nd], 0, 0, 0);
    }
  }

  // ---- store O: row i = mi*16+q4*4+reg, col d = nd*16+r ----
  #pragma unroll
  for (int mi = 0; mi < 4; mi++)
    #pragma unroll
    for (int nd = 0; nd < 2; nd++)
      #pragma unroll
      for (int reg = 0; reg < 4; reg++) {
        const int i = mi * 16 + q4 * 4 + reg;
        outb[((size_t)w * 64 + i) * DIM + h * 32 + nd * 16 + r] =
            __float2bfloat16(oacc[mi][nd][reg]);
      }
}

// ---------------- host launch ----------------
extern "C" void kernel_launch(void* const* d_in, const int* in_sizes, int n_in,
                              void* d_out, int out_size, void* d_ws, size_t ws_size,
                              hipStream_t stream) {
  const float* x      = (const float*)d_in[0];
  const float* ln1_g  = (const float*)d_in[3];
  const float* ln1_b  = (const float*)d_in[4];
  const float* qkv_w  = (const float*)d_in[5];
  const float* qkv_b  = (const float*)d_in[6];
  const float* proj_w = (const float*)d_in[7];
  const float* proj_b = (const float*)d_in[8];
  const float* tau    = (const float*)d_in[9];
  const float* rpb    = (const float*)d_in[10];
  const float* ln2_g  = (const float*)d_in[11];
  const float* ln2_b  = (const float*)d_in[12];
  const float* fc1_w  = (const float*)d_in[13];
  const float* fc1_b  = (const float*)d_in[14];
  const float* fc2_w  = (const float*)d_in[15];
  const float* fc2_b  = (const float*)d_in[16];
  float* out = (float*)d_out;
  char* ws = (char*)d_ws;

  bf16* wT_qkv  = (bf16*)(ws + 0);
  bf16* wT_proj = (bf16*)(ws + 884736);
  bf16* wT_fc1  = (bf16*)(ws + 1179648);
  bf16* wT_fc2  = (bf16*)(ws + 2359296);
  bf16* winb    = (bf16*)(ws + 4194304);
  bf16* qkvb    = (bf16*)(ws + 54525952);
  bf16* attnb   = (bf16*)(ws + 205520896);
  bf16* xn2b    = winb;
  bf16* hb      = qkvb;

  wconv_kernel<<<(384 * 1152 + 255) / 256, 256, 0, stream>>>(qkv_w, wT_qkv, 384, 1152);
  wconv_kernel<<<(384 * 384 + 255) / 256, 256, 0, stream>>>(proj_w, wT_proj, 384, 384);
  wconv_kernel<<<(384 * 1536 + 255) / 256, 256, 0, stream>>>(fc1_w, wT_fc1, 384, 1536);
  wconv_kernel<<<(1536 * 384 + 255) / 256, 256, 0, stream>>>(fc2_w, wT_fc2, 1536, 384);

  ln_kernel<<<MTOT, 384, 0, stream>>>(x, ln1_g, ln1_b, winb, 1);
  gemm_bt<0><<<(MTOT / 128) * (1152 / 128), 512, 0, stream>>>(
      winb, wT_qkv, qkv_b, qkvb, nullptr, nullptr, MTOT, 1152, 384, 1152 / 128);
  attn_kernel<<<dim3(3, 1024), 256, 0, stream>>>(qkvb, tau, rpb, attnb);
  gemm_bt<2><<<(MTOT / 128) * (384 / 128), 512, 0, stream>>>(
      attnb, wT_proj, proj_b, nullptr, out, x, MTOT, 384, 384, 384 / 128);
  ln_kernel<<<MTOT, 384, 0, stream>>>(out, ln2_g, ln2_b, xn2b, 0);
  gemm_bt<1><<<(MTOT / 128) * (HID / 128), 512, 0, stream>>>(
      xn2b, wT_fc1, fc1_b, hb, nullptr, nullptr, MTOT, HID, 384, HID / 128);
  gemm_bt<3><<<(MTOT / 128) * (384 / 128), 512, 0, stream>>>(
      hb, wT_fc2, fc2_b, nullptr, out, nullptr, MTOT, 384, HID, 384 / 128);
}

// Round 6
// 840.216 us; speedup vs baseline: 1.1749x; 1.0051x over previous
//
#include <hip/hip_runtime.h>
#include <hip/hip_bf16.h>
#include <cstdint>

// ---------------- constants ----------------
#define DIM     384
#define NHEADS  12
#define HD      32
#define HGRID   64          // H = W = 64
#define NTOK    64          // tokens per 8x8 window
#define MTOT    65536       // 16 * 4096 rows
#define HID     1536

typedef __attribute__((ext_vector_type(8))) short bf16x8;
typedef __attribute__((ext_vector_type(4))) float f32x4;
typedef __hip_bfloat16 bf16;

typedef __attribute__((address_space(1))) const void* as1_cvp;
typedef __attribute__((address_space(3))) void*       as3_vp;
#define GLDS16(g, l) __builtin_amdgcn_global_load_lds((as1_cvp)(g), (as3_vp)(l), 16, 0, 0)

__device__ __forceinline__ float bf2f(short s) {
  union { unsigned int u; float f; } x;
  x.u = ((unsigned int)(unsigned short)s) << 16;
  return x.f;
}
__device__ __forceinline__ unsigned int f2u(float f) {
  union { bf16 b; unsigned short s; } c;
  c.b = __float2bfloat16(f);
  return (unsigned int)c.s;
}

// ---------------- K0: weight fp32 (KxN) -> bf16 transposed (NxK) ----------------
__global__ void wconv_kernel(const float* __restrict__ src, bf16* __restrict__ dst,
                             int K, int N) {
  int i = blockIdx.x * 256 + threadIdx.x;
  if (i >= K * N) return;
  int n = i / K, k = i - n * K;
  dst[i] = __float2bfloat16(src[(size_t)k * N + n]);
}

// ---------------- K1/K5: LayerNorm (optionally fused roll+window gather) ----------
__global__ __launch_bounds__(384) void ln_kernel(const float* __restrict__ x,
    const float* __restrict__ g, const float* __restrict__ bta,
    bf16* __restrict__ out, int windowed) {
  const int row = blockIdx.x;
  const int c = threadIdx.x;
  size_t src;
  if (windowed) {
    int wg = row >> 6, n = row & 63;
    int b = wg >> 6, wi = wg & 63;
    int hp = ((wi >> 3) << 3) + (n >> 3);
    int wp = ((wi & 7) << 3) + (n & 7);
    int h = (hp + 4) & 63, w = (wp + 4) & 63;   // roll(-4): rolled[i] = x[(i+4)%64]
    src = ((size_t)b * 4096 + h * 64 + w) * DIM;
  } else {
    src = (size_t)row * DIM;
  }
  float v = x[src + c];
  float s = v, ss = v * v;
  #pragma unroll
  for (int off = 32; off; off >>= 1) {
    s  += __shfl_xor(s,  off, 64);
    ss += __shfl_xor(ss, off, 64);
  }
  __shared__ float red[12];
  const int wave = threadIdx.x >> 6, lane = threadIdx.x & 63;
  if (lane == 0) { red[wave] = s; red[6 + wave] = ss; }
  __syncthreads();
  if (threadIdx.x == 0) {
    float ts = 0.f, tss = 0.f;
    #pragma unroll
    for (int i = 0; i < 6; i++) { ts += red[i]; tss += red[6 + i]; }
    red[0] = ts; red[6] = tss;
  }
  __syncthreads();
  const float mean = red[0] * (1.0f / DIM);
  const float var  = red[6] * (1.0f / DIM) - mean * mean;
  const float inv  = rsqrtf(var + 1e-5f);
  out[(size_t)row * DIM + c] = __float2bfloat16((v - mean) * inv * g[c] + bta[c]);
}

// ---------------- GEMM: C = A(MxK) * Bt(NxK)^T, bf16 MFMA 16x16x32 ---------------
// 512 thr / 8 waves, 128x128 tile, BK=64, double-buffered.
// R9: COUNTED-VMCNT pipeline (T4). R5 counters (MFMA 19.6 / VALU 15 / HBM 21% /
// occ 42, zero conflicts) showed the per-step __syncthreads drain (vmcnt(0))
// still exposed full HBM latency: per-step ~ compute + ~900cy. These GEMMs are
// skinny-K streamers (compute/step ~300cy vs ~3200cy of memory) -- Little's law
// needs loads continuously in flight. New loop (m201-verified pattern):
//   issue GLDS t+1 -> buf^1 ; s_waitcnt vmcnt(4)  [t ready, t+1 IN FLIGHT]
//   s_barrier ; ds_read+MFMA buf[cur] ; s_barrier  [protects buf before t+2]
// Tail iter waits vmcnt(0). sched_barrier(0) after waitcnt (rule 18).
// Race audit: reads of tile t-1 complete before iter t-1's 2nd barrier; iter
// t's GLDS into that buffer issues after it.
// EPI: 0 = +bias -> bf16 | 1 = +bias,GELU -> bf16 | 2 = +bias, window-reverse
// +roll scatter +resid -> f32 | 3 = +bias, += f32 out
template <int EPI>
__global__ __launch_bounds__(512) void gemm_bt(
    const bf16* __restrict__ A, const bf16* __restrict__ Bt,
    const float* __restrict__ bias,
    bf16* __restrict__ outb, float* __restrict__ outf,
    const float* __restrict__ resid,
    int M, int N, int K, int gridN)
{
  __shared__ bf16 As[2][128 * 64];
  __shared__ bf16 Bs[2][128 * 64];
  const int tid = threadIdx.x;
  const int wave = tid >> 6, lane = tid & 63;

  const int bid = blockIdx.x;
  const int xcd = bid & 7, slot = bid >> 3;
  const int n_blk = slot % gridN;
  const int m_blk = (slot / gridN) * 8 + xcd;
  const int m0 = m_blk * 128, n0 = n_blk * 128;

  f32x4 acc[4][2];
  #pragma unroll
  for (int i = 0; i < 4; i++)
    #pragma unroll
    for (int j = 0; j < 2; j++) acc[i][j] = (f32x4){0.f, 0.f, 0.f, 0.f};

  const int q = lane >> 4, r = lane & 15;
  const int mwav = (wave >> 2) * 64;
  const int nwav = (wave & 3) * 32;

  const int srow = wave * 16 + (lane >> 3);
  const int gchunk = (lane & 7) ^ ((lane >> 3) & 7);
  const char* Ac = (const char*)A + (size_t)(m0 + srow) * K * 2 + gchunk * 16;
  const char* Bc = (const char*)Bt + (size_t)(n0 + srow) * K * 2 + gchunk * 16;
  const size_t rowskip8 = (size_t)8 * K * 2;
  const int ldsbase = wave * 16 * 64;

  const int rxor = r & 7;
  const int nt = K >> 6;

  // prologue: issue tile 0, NO drain (iter 0's vmcnt+barrier covers it)
  {
    bf16* Ad = &As[0][ldsbase];
    bf16* Bd = &Bs[0][ldsbase];
    GLDS16(Ac,            Ad + 0 * 64);
    GLDS16(Ac + rowskip8, Ad + 8 * 64);
    GLDS16(Bc,            Bd + 0 * 64);
    GLDS16(Bc + rowskip8, Bd + 8 * 64);
  }

  int cur = 0;
  for (int t = 0; t < nt; ++t) {
    if (t + 1 < nt) {
      const size_t kb = (size_t)(t + 1) * 128;
      bf16* Ad = &As[cur ^ 1][ldsbase];
      bf16* Bd = &Bs[cur ^ 1][ldsbase];
      GLDS16(Ac + kb,            Ad + 0 * 64);
      GLDS16(Ac + kb + rowskip8, Ad + 8 * 64);
      GLDS16(Bc + kb,            Bd + 0 * 64);
      GLDS16(Bc + kb + rowskip8, Bd + 8 * 64);
      asm volatile("s_waitcnt vmcnt(4)" ::: "memory");   // tile t landed; t+1 in flight
    } else {
      asm volatile("s_waitcnt vmcnt(0)" ::: "memory");   // tail: last tile landed
    }
    __builtin_amdgcn_sched_barrier(0);
    __builtin_amdgcn_s_barrier();                        // all waves' tile-t loads visible

    const bf16* Ar = As[cur];
    const bf16* Br = Bs[cur];
    #pragma unroll
    for (int hh = 0; hh < 2; hh++) {
      const int s = (hh * 4 + q) ^ rxor;
      bf16x8 af[4], bfr[2];
      #pragma unroll
      for (int mi = 0; mi < 4; mi++)
        af[mi] = *(const bf16x8*)(&Ar[(mwav + mi * 16 + r) * 64 + s * 8]);
      #pragma unroll
      for (int ni = 0; ni < 2; ni++)
        bfr[ni] = *(const bf16x8*)(&Br[(nwav + ni * 16 + r) * 64 + s * 8]);
      #pragma unroll
      for (int mi = 0; mi < 4; mi++)
        #pragma unroll
        for (int ni = 0; ni < 2; ni++)
          acc[mi][ni] = __builtin_amdgcn_mfma_f32_16x16x32_bf16(af[mi], bfr[ni], acc[mi][ni], 0, 0, 0);
    }

    __builtin_amdgcn_s_barrier();   // all reads of buf[cur] done before t+2 overwrite
    cur ^= 1;
  }

  #pragma unroll
  for (int mi = 0; mi < 4; mi++) {
    #pragma unroll
    for (int ni = 0; ni < 2; ni++) {
      #pragma unroll
      for (int rr = 0; rr < 4; rr++) {
        const int row = m0 + mwav + mi * 16 + q * 4 + rr;
        const int col = n0 + nwav + ni * 16 + r;
        float val = acc[mi][ni][rr] + bias[col];
        if (EPI == 0) {
          outb[(size_t)row * N + col] = __float2bfloat16(val);
        } else if (EPI == 1) {
          const float t = val * val;
          const float z = val * fmaf(t, 0.07135481283f, 1.5957691216f);
          const float gl = val / (1.0f + __expf(-z));
          outb[(size_t)row * N + col] = __float2bfloat16(gl);
        } else if (EPI == 2) {
          const int wg = row >> 6, n = row & 63;
          const int b = wg >> 6, wi = wg & 63;
          const int hp = ((wi >> 3) << 3) + (n >> 3);
          const int wp = ((wi & 7) << 3) + (n & 7);
          const int h = (hp + 4) & 63, w = (wp + 4) & 63;
          const size_t dst = ((size_t)b * 4096 + h * 64 + w) * DIM + col;
          outf[dst] = resid[dst] + val;
        } else {
          outf[(size_t)row * N + col] += val;
        }
      }
    }
  }
}

// ---------------- K3: MFMA windowed attention, ONE WAVE per (window, head) -------
// (unchanged from R5: S^T=mfma(K,Q), post-MFMA scaling, in-lane softmax,
// swizzled P LDS, V^T scatter-gather issued early, PV on MFMA.)
__device__ __forceinline__ int regid(int v) { return v < 56 ? 0 : (v < 60 ? 1 : 2); }

__global__ __launch_bounds__(256, 2) void attn_kernel(
    const bf16* __restrict__ qkv, const float* __restrict__ tau,
    const float* __restrict__ rpb, bf16* __restrict__ outb)
{
  const int wv = threadIdx.x >> 6;
  const int lane = threadIdx.x & 63;
  const int q4 = lane >> 4, r = lane & 15;
  const int h = blockIdx.x * 4 + wv;       // head
  const int w = blockIdx.y;                // global window

  __shared__ bf16  pbuf[4][64 * 64];       // 8 KB per wave, swizzled P
  __shared__ float rpb_s[4][228];
  __shared__ float kscs[4][64];

  for (int t = lane; t < 225; t += 64)
    rpb_s[wv][t] = rpb[t * NHEADS + h];

  const size_t rowbase = ((size_t)w * 64) * 1152 + (size_t)h * 32;
  bf16x8 qf[4], kf[4];
  #pragma unroll
  for (int mi = 0; mi < 4; mi++) {
    const size_t ro = rowbase + (size_t)(mi * 16 + r) * 1152 + q4 * 8;
    qf[mi] = *(const bf16x8*)(qkv + ro);
    kf[mi] = *(const bf16x8*)(qkv + ro + 384);
  }

  const bf16* vbase = qkv + rowbase + 768;
  unsigned short vraw[2][2][8];
  #pragma unroll
  for (int ks = 0; ks < 2; ks++)
    #pragma unroll
    for (int nd = 0; nd < 2; nd++)
      #pragma unroll
      for (int t = 0; t < 8; t++)
        vraw[ks][nd][t] = *(const unsigned short*)(vbase +
            (size_t)(ks * 32 + q4 * 8 + t) * 1152 + nd * 16 + r);

  float qsc[4];
  {
    const float tinv = 1.0f / fmaxf(tau[h], 1e-3f);
    #pragma unroll
    for (int mi = 0; mi < 4; mi++) {
      float sq = 0.f, sk = 0.f;
      #pragma unroll
      for (int e = 0; e < 8; e++) {
        float a = bf2f(qf[mi][e]), b = bf2f(kf[mi][e]);
        sq = fmaf(a, a, sq); sk = fmaf(b, b, sk);
      }
      sq += __shfl_xor(sq, 16, 64); sq += __shfl_xor(sq, 32, 64);
      sk += __shfl_xor(sk, 16, 64); sk += __shfl_xor(sk, 32, 64);
      qsc[mi] = tinv / fmaxf(sqrtf(sq), 1e-12f);
      if (q4 == 0) kscs[wv][mi * 16 + r] = 1.0f / fmaxf(sqrtf(sk), 1e-12f);
    }
  }

  f32x4 sacc[4][4];
  #pragma unroll
  for (int a = 0; a < 4; a++)
    #pragma unroll
    for (int b = 0; b < 4; b++) sacc[a][b] = (f32x4){0.f, 0.f, 0.f, 0.f};
  #pragma unroll
  for (int mj = 0; mj < 4; mj++)
    #pragma unroll
    for (int mi = 0; mi < 4; mi++)
      sacc[mj][mi] = __builtin_amdgcn_mfma_f32_16x16x32_bf16(kf[mj], qf[mi], sacc[mj][mi], 0, 0, 0);

  const int wi = w & 63, wy = wi >> 3, wx = wi & 7;
  int byi[4], regi[4];
  #pragma unroll
  for (int mi = 0; mi < 4; mi++) {
    const int i = mi * 16 + r, iy = i >> 3, ix = i & 7;
    byi[mi]  = (iy + 7) * 15 + (ix + 7);
    regi[mi] = regid(wy * 8 + iy) * 3 + regid(wx * 8 + ix);
  }
  float kscv[4][4];
  #pragma unroll
  for (int mj = 0; mj < 4; mj++)
    #pragma unroll
    for (int reg = 0; reg < 4; reg++)
      kscv[mj][reg] = kscs[wv][mj * 16 + q4 * 4 + reg];

  float mx[4] = {-3e38f, -3e38f, -3e38f, -3e38f};
  #pragma unroll
  for (int mj = 0; mj < 4; mj++) {
    #pragma unroll
    for (int reg = 0; reg < 4; reg++) {
      const int j = mj * 16 + q4 * 4 + reg;
      const int jy = j >> 3, jx = j & 7;
      const int offj = jy * 15 + jx;
      const int regj = regid(wy * 8 + jy) * 3 + regid(wx * 8 + jx);
      const float kv = kscv[mj][reg];
      #pragma unroll
      for (int mi = 0; mi < 4; mi++) {
        float v = sacc[mj][mi][reg] * (qsc[mi] * kv) + rpb_s[wv][byi[mi] - offj];
        if (regj != regi[mi]) v -= 1e9f;
        sacc[mj][mi][reg] = v;
        mx[mi] = fmaxf(mx[mi], v);
      }
    }
  }
  float sum[4] = {0.f, 0.f, 0.f, 0.f};
  #pragma unroll
  for (int mi = 0; mi < 4; mi++) {
    mx[mi] = fmaxf(mx[mi], __shfl_xor(mx[mi], 16, 64));
    mx[mi] = fmaxf(mx[mi], __shfl_xor(mx[mi], 32, 64));
  }
  #pragma unroll
  for (int mj = 0; mj < 4; mj++)
    #pragma unroll
    for (int mi = 0; mi < 4; mi++)
      #pragma unroll
      for (int reg = 0; reg < 4; reg++) {
        float p = __expf(sacc[mj][mi][reg] - mx[mi]);
        sacc[mj][mi][reg] = p;
        sum[mi] += p;
      }
  float rinv[4];
  #pragma unroll
  for (int mi = 0; mi < 4; mi++) {
    sum[mi] += __shfl_xor(sum[mi], 16, 64);
    sum[mi] += __shfl_xor(sum[mi], 32, 64);
    rinv[mi] = 1.0f / sum[mi];
  }

  #pragma unroll
  for (int mj = 0; mj < 4; mj++) {
    #pragma unroll
    for (int mi = 0; mi < 4; mi++) {
      const int i = mi * 16 + r;
      const int cs = (mj * 4 + q4) ^ r;
      uint2 d;
      d.x = f2u(sacc[mj][mi][0] * rinv[mi]) | (f2u(sacc[mj][mi][1] * rinv[mi]) << 16);
      d.y = f2u(sacc[mj][mi][2] * rinv[mi]) | (f2u(sacc[mj][mi][3] * rinv[mi]) << 16);
      *(uint2*)(&pbuf[wv][i * 64 + cs * 4]) = d;
    }
  }

  bf16x8 vf[2][2];
  #pragma unroll
  for (int ks = 0; ks < 2; ks++)
    #pragma unroll
    for (int nd = 0; nd < 2; nd++) {
      union { unsigned int u[4]; bf16x8 v; } t;
      #pragma unroll
      for (int e = 0; e < 4; e++)
        t.u[e] = (unsigned int)vraw[ks][nd][2 * e] |
                 ((unsigned int)vraw[ks][nd][2 * e + 1] << 16);
      vf[ks][nd] = t.v;
    }

  f32x4 oacc[4][2];
  #pragma unroll
  for (int a = 0; a < 4; a++)
    #pragma unroll
    for (int b = 0; b < 2; b++) oacc[a][b] = (f32x4){0.f, 0.f, 0.f, 0.f};
  #pragma unroll
  for (int mi = 0; mi < 4; mi++) {
    const int i = mi * 16 + r;
    #pragma unroll
    for (int ks = 0; ks < 2; ks++) {
      const int c1 = (ks * 8 + q4 * 2) ^ r;
      const int c2 = (ks * 8 + q4 * 2 + 1) ^ r;
      union { unsigned int u[4]; bf16x8 v; } pf;
      uint2 lo = *(const uint2*)(&pbuf[wv][i * 64 + c1 * 4]);
      uint2 hi = *(const uint2*)(&pbuf[wv][i * 64 + c2 * 4]);
      pf.u[0] = lo.x; pf.u[1] = lo.y; pf.u[2] = hi.x; pf.u[3] = hi.y;
      #pragma unroll
      for (int nd = 0; nd < 2; nd++)
        oacc[mi][nd] = __builtin_amdgcn_mfma_f32_16x16x32_bf16(pf.v, vf[ks][nd], oacc[mi][nd], 0, 0, 0);
    }
  }

  #pragma unroll
  for (int mi = 0; mi < 4; mi++)
    #pragma unroll
    for (int nd = 0; nd < 2; nd++)
      #pragma unroll
      for (int reg = 0; reg < 4; reg++) {
        const int i = mi * 16 + q4 * 4 + reg;
        outb[((size_t)w * 64 + i) * DIM + h * 32 + nd * 16 + r] =
            __float2bfloat16(oacc[mi][nd][reg]);
      }
}

// ---------------- host launch ----------------
extern "C" void kernel_launch(void* const* d_in, const int* in_sizes, int n_in,
                              void* d_out, int out_size, void* d_ws, size_t ws_size,
                              hipStream_t stream) {
  const float* x      = (const float*)d_in[0];
  const float* ln1_g  = (const float*)d_in[3];
  const float* ln1_b  = (const float*)d_in[4];
  const float* qkv_w  = (const float*)d_in[5];
  const float* qkv_b  = (const float*)d_in[6];
  const float* proj_w = (const float*)d_in[7];
  const float* proj_b = (const float*)d_in[8];
  const float* tau    = (const float*)d_in[9];
  const float* rpb    = (const float*)d_in[10];
  const float* ln2_g  = (const float*)d_in[11];
  const float* ln2_b  = (const float*)d_in[12];
  const float* fc1_w  = (const float*)d_in[13];
  const float* fc1_b  = (const float*)d_in[14];
  const float* fc2_w  = (const float*)d_in[15];
  const float* fc2_b  = (const float*)d_in[16];
  float* out = (float*)d_out;
  char* ws = (char*)d_ws;

  bf16* wT_qkv  = (bf16*)(ws + 0);
  bf16* wT_proj = (bf16*)(ws + 884736);
  bf16* wT_fc1  = (bf16*)(ws + 1179648);
  bf16* wT_fc2  = (bf16*)(ws + 2359296);
  bf16* winb    = (bf16*)(ws + 4194304);
  bf16* qkvb    = (bf16*)(ws + 54525952);
  bf16* attnb   = (bf16*)(ws + 205520896);
  bf16* xn2b    = winb;
  bf16* hb      = qkvb;

  wconv_kernel<<<(384 * 1152 + 255) / 256, 256, 0, stream>>>(qkv_w, wT_qkv, 384, 1152);
  wconv_kernel<<<(384 * 384 + 255) / 256, 256, 0, stream>>>(proj_w, wT_proj, 384, 384);
  wconv_kernel<<<(384 * 1536 + 255) / 256, 256, 0, stream>>>(fc1_w, wT_fc1, 384, 1536);
  wconv_kernel<<<(1536 * 384 + 255) / 256, 256, 0, stream>>>(fc2_w, wT_fc2, 1536, 384);

  ln_kernel<<<MTOT, 384, 0, stream>>>(x, ln1_g, ln1_b, winb, 1);
  gemm_bt<0><<<(MTOT / 128) * (1152 / 128), 512, 0, stream>>>(
      winb, wT_qkv, qkv_b, qkvb, nullptr, nullptr, MTOT, 1152, 384, 1152 / 128);
  attn_kernel<<<dim3(3, 1024), 256, 0, stream>>>(qkvb, tau, rpb, attnb);
  gemm_bt<2><<<(MTOT / 128) * (384 / 128), 512, 0, stream>>>(
      attnb, wT_proj, proj_b, nullptr, out, x, MTOT, 384, 384, 384 / 128);
  ln_kernel<<<MTOT, 384, 0, stream>>>(out, ln2_g, ln2_b, xn2b, 0);
  gemm_bt<1><<<(MTOT / 128) * (HID / 128), 512, 0, stream>>>(
      xn2b, wT_fc1, fc1_b, hb, nullptr, nullptr, MTOT, HID, 384, HID / 128);
  gemm_bt<3><<<(MTOT / 128) * (384 / 128), 512, 0, stream>>>(
      hb, wT_fc2, fc2_b, nullptr, out, nullptr, MTOT, 384, HID, 384 / 128);
}

// Round 7
// 711.887 us; speedup vs baseline: 1.3867x; 1.1803x over previous
//
#include <hip/hip_runtime.h>
#include <hip/hip_bf16.h>
#include <cstdint>

// ---------------- constants ----------------
#define DIM     384
#define NHEADS  12
#define HD      32
#define HGRID   64          // H = W = 64
#define NTOK    64          // tokens per 8x8 window
#define MTOT    65536       // 16 * 4096 rows
#define HID     1536

typedef __attribute__((ext_vector_type(8))) short bf16x8;
typedef __attribute__((ext_vector_type(4))) float f32x4;
typedef __hip_bfloat16 bf16;

typedef __attribute__((address_space(1))) const void* as1_cvp;
typedef __attribute__((address_space(3))) void*       as3_vp;
#define GLDS16(g, l) __builtin_amdgcn_global_load_lds((as1_cvp)(g), (as3_vp)(l), 16, 0, 0)

__device__ __forceinline__ float bf2f(short s) {
  union { unsigned int u; float f; } x;
  x.u = ((unsigned int)(unsigned short)s) << 16;
  return x.f;
}
__device__ __forceinline__ unsigned int f2u(float f) {
  union { bf16 b; unsigned short s; } c;
  c.b = __float2bfloat16(f);
  return (unsigned int)c.s;
}
__device__ __forceinline__ unsigned short f2us(float f) {
  union { bf16 b; unsigned short s; } c;
  c.b = __float2bfloat16(f);
  return c.s;
}

// ---------------- K0: weight fp32 (KxN) -> bf16 transposed (NxK) ----------------
__global__ void wconv_kernel(const float* __restrict__ src, bf16* __restrict__ dst,
                             int K, int N) {
  int i = blockIdx.x * 256 + threadIdx.x;
  if (i >= K * N) return;
  int n = i / K, k = i - n * K;
  dst[i] = __float2bfloat16(src[(size_t)k * N + n]);
}

// ---------------- K1: LN1 + roll + window gather, WAVE-PER-ROW -------------------
// R10: wave-per-row (4 rows / 256-thr block, lane holds 6 channels, wave-local
// shfl reduce, no LDS/barrier). Old 384-thr-per-row scalar form was
// reduction/occupancy-bound.
__global__ __launch_bounds__(256) void ln1_kernel(const float* __restrict__ x,
    const float* __restrict__ g, const float* __restrict__ bta,
    bf16* __restrict__ out) {
  const int row = blockIdx.x * 4 + (threadIdx.x >> 6);   // windowed output row
  const int lane = threadIdx.x & 63;
  const int c0 = lane * 6;

  // windowed gather: row -> source phys row (roll -4)
  const int wg = row >> 6, n = row & 63;
  const int b = wg >> 6, wi = wg & 63;
  const int hp = ((wi >> 3) << 3) + (n >> 3);
  const int wp = ((wi & 7) << 3) + (n & 7);
  const int h = (hp + 4) & 63, w = (wp + 4) & 63;
  const float* xr = x + ((size_t)b * 4096 + h * 64 + w) * DIM + c0;

  float v[6];
  {
    float2 a0 = *(const float2*)(xr);
    float2 a1 = *(const float2*)(xr + 2);
    float2 a2 = *(const float2*)(xr + 4);
    v[0] = a0.x; v[1] = a0.y; v[2] = a1.x; v[3] = a1.y; v[4] = a2.x; v[5] = a2.y;
  }
  float s = 0.f, ss = 0.f;
  #pragma unroll
  for (int i = 0; i < 6; i++) { s += v[i]; ss = fmaf(v[i], v[i], ss); }
  #pragma unroll
  for (int off = 32; off; off >>= 1) {
    s  += __shfl_xor(s,  off, 64);
    ss += __shfl_xor(ss, off, 64);
  }
  const float mean = s * (1.0f / DIM);
  const float var  = ss * (1.0f / DIM) - mean * mean;
  const float inv  = rsqrtf(var + 1e-5f);

  const float* gp = g + c0;
  const float* bp = bta + c0;
  unsigned short o[6];
  #pragma unroll
  for (int i = 0; i < 6; i++)
    o[i] = f2us((v[i] - mean) * inv * gp[i] + bp[i]);
  bf16* op = out + (size_t)row * DIM + c0;
  *(ushort2*)(op)     = make_ushort2(o[0], o[1]);
  *(ushort2*)(op + 2) = make_ushort2(o[2], o[3]);
  *(ushort2*)(op + 4) = make_ushort2(o[4], o[5]);
}

// ---------------- K5: fused residual + window-reverse/roll gather + LN2 ----------
// R10: replaces proj's EPI=2 scatter epilogue (the R6 anomaly: proj at 26% BW,
// 200 of its 265 MB was serial scattered 4B RMW) AND the old LN2 pass.
// Phys row: out = x + projb[win_src(row)] (f32), xn2b = LN(out) (bf16).
// projb rows are contiguous 768 B gathers; all other traffic streams.
__global__ __launch_bounds__(256) void resid_ln2_kernel(const float* __restrict__ x,
    const bf16* __restrict__ projb,
    const float* __restrict__ g, const float* __restrict__ bta,
    float* __restrict__ out, bf16* __restrict__ xn2) {
  const int row = blockIdx.x * 4 + (threadIdx.x >> 6);   // phys row
  const int lane = threadIdx.x & 63;
  const int c0 = lane * 6;

  // inverse window map: phys (b,hh,ww) -> windowed source row (roll +4 inverse)
  const int b = row >> 12, r12 = row & 4095;
  const int hh = r12 >> 6, ww = r12 & 63;
  const int hp = (hh + 60) & 63, wp = (ww + 60) & 63;
  const int wi = ((hp >> 3) << 3) + (wp >> 3);
  const int n  = ((hp & 7) << 3) + (wp & 7);
  const bf16* pr = projb + ((size_t)b * 4096 + wi * 64 + n) * DIM + c0;
  const float* xr = x + (size_t)row * DIM + c0;

  float v[6];
  {
    float2 a0 = *(const float2*)(xr);
    float2 a1 = *(const float2*)(xr + 2);
    float2 a2 = *(const float2*)(xr + 4);
    ushort2 p0 = *(const ushort2*)(pr);
    ushort2 p1 = *(const ushort2*)(pr + 2);
    ushort2 p2 = *(const ushort2*)(pr + 4);
    v[0] = a0.x + bf2f(p0.x); v[1] = a0.y + bf2f(p0.y);
    v[2] = a1.x + bf2f(p1.x); v[3] = a1.y + bf2f(p1.y);
    v[4] = a2.x + bf2f(p2.x); v[5] = a2.y + bf2f(p2.y);
  }
  // residual out (f32)
  float* orow = out + (size_t)row * DIM + c0;
  *(float2*)(orow)     = make_float2(v[0], v[1]);
  *(float2*)(orow + 2) = make_float2(v[2], v[3]);
  *(float2*)(orow + 4) = make_float2(v[4], v[5]);

  float s = 0.f, ss = 0.f;
  #pragma unroll
  for (int i = 0; i < 6; i++) { s += v[i]; ss = fmaf(v[i], v[i], ss); }
  #pragma unroll
  for (int off = 32; off; off >>= 1) {
    s  += __shfl_xor(s,  off, 64);
    ss += __shfl_xor(ss, off, 64);
  }
  const float mean = s * (1.0f / DIM);
  const float var  = ss * (1.0f / DIM) - mean * mean;
  const float inv  = rsqrtf(var + 1e-5f);

  const float* gp = g + c0;
  const float* bp = bta + c0;
  unsigned short o[6];
  #pragma unroll
  for (int i = 0; i < 6; i++)
    o[i] = f2us((v[i] - mean) * inv * gp[i] + bp[i]);
  bf16* op = xn2 + (size_t)row * DIM + c0;
  *(ushort2*)(op)     = make_ushort2(o[0], o[1]);
  *(ushort2*)(op + 2) = make_ushort2(o[2], o[3]);
  *(ushort2*)(op + 4) = make_ushort2(o[4], o[5]);
}

// ---------------- GEMM: C = A(MxK) * Bt(NxK)^T, bf16 MFMA 16x16x32 ---------------
// 512 thr / 8 waves, 128x128 tile, BK=64, double-buffered, counted vmcnt (R9;
// measured == __syncthreads version, kept).
// EPI: 0 = +bias -> bf16 | 1 = +bias,GELU -> bf16 | 3 = +bias, += f32 out
template <int EPI>
__global__ __launch_bounds__(512) void gemm_bt(
    const bf16* __restrict__ A, const bf16* __restrict__ Bt,
    const float* __restrict__ bias,
    bf16* __restrict__ outb, float* __restrict__ outf,
    const float* __restrict__ resid,
    int M, int N, int K, int gridN)
{
  __shared__ bf16 As[2][128 * 64];
  __shared__ bf16 Bs[2][128 * 64];
  const int tid = threadIdx.x;
  const int wave = tid >> 6, lane = tid & 63;

  const int bid = blockIdx.x;
  const int xcd = bid & 7, slot = bid >> 3;
  const int n_blk = slot % gridN;
  const int m_blk = (slot / gridN) * 8 + xcd;
  const int m0 = m_blk * 128, n0 = n_blk * 128;

  f32x4 acc[4][2];
  #pragma unroll
  for (int i = 0; i < 4; i++)
    #pragma unroll
    for (int j = 0; j < 2; j++) acc[i][j] = (f32x4){0.f, 0.f, 0.f, 0.f};

  const int q = lane >> 4, r = lane & 15;
  const int mwav = (wave >> 2) * 64;
  const int nwav = (wave & 3) * 32;

  const int srow = wave * 16 + (lane >> 3);
  const int gchunk = (lane & 7) ^ ((lane >> 3) & 7);
  const char* Ac = (const char*)A + (size_t)(m0 + srow) * K * 2 + gchunk * 16;
  const char* Bc = (const char*)Bt + (size_t)(n0 + srow) * K * 2 + gchunk * 16;
  const size_t rowskip8 = (size_t)8 * K * 2;
  const int ldsbase = wave * 16 * 64;

  const int rxor = r & 7;
  const int nt = K >> 6;

  {
    bf16* Ad = &As[0][ldsbase];
    bf16* Bd = &Bs[0][ldsbase];
    GLDS16(Ac,            Ad + 0 * 64);
    GLDS16(Ac + rowskip8, Ad + 8 * 64);
    GLDS16(Bc,            Bd + 0 * 64);
    GLDS16(Bc + rowskip8, Bd + 8 * 64);
  }

  int cur = 0;
  for (int t = 0; t < nt; ++t) {
    if (t + 1 < nt) {
      const size_t kb = (size_t)(t + 1) * 128;
      bf16* Ad = &As[cur ^ 1][ldsbase];
      bf16* Bd = &Bs[cur ^ 1][ldsbase];
      GLDS16(Ac + kb,            Ad + 0 * 64);
      GLDS16(Ac + kb + rowskip8, Ad + 8 * 64);
      GLDS16(Bc + kb,            Bd + 0 * 64);
      GLDS16(Bc + kb + rowskip8, Bd + 8 * 64);
      asm volatile("s_waitcnt vmcnt(4)" ::: "memory");
    } else {
      asm volatile("s_waitcnt vmcnt(0)" ::: "memory");
    }
    __builtin_amdgcn_sched_barrier(0);
    __builtin_amdgcn_s_barrier();

    const bf16* Ar = As[cur];
    const bf16* Br = Bs[cur];
    #pragma unroll
    for (int hh = 0; hh < 2; hh++) {
      const int s = (hh * 4 + q) ^ rxor;
      bf16x8 af[4], bfr[2];
      #pragma unroll
      for (int mi = 0; mi < 4; mi++)
        af[mi] = *(const bf16x8*)(&Ar[(mwav + mi * 16 + r) * 64 + s * 8]);
      #pragma unroll
      for (int ni = 0; ni < 2; ni++)
        bfr[ni] = *(const bf16x8*)(&Br[(nwav + ni * 16 + r) * 64 + s * 8]);
      #pragma unroll
      for (int mi = 0; mi < 4; mi++)
        #pragma unroll
        for (int ni = 0; ni < 2; ni++)
          acc[mi][ni] = __builtin_amdgcn_mfma_f32_16x16x32_bf16(af[mi], bfr[ni], acc[mi][ni], 0, 0, 0);
    }

    __builtin_amdgcn_s_barrier();
    cur ^= 1;
  }

  #pragma unroll
  for (int mi = 0; mi < 4; mi++) {
    #pragma unroll
    for (int ni = 0; ni < 2; ni++) {
      #pragma unroll
      for (int rr = 0; rr < 4; rr++) {
        const int row = m0 + mwav + mi * 16 + q * 4 + rr;
        const int col = n0 + nwav + ni * 16 + r;
        float val = acc[mi][ni][rr] + bias[col];
        if (EPI == 0) {
          outb[(size_t)row * N + col] = __float2bfloat16(val);
        } else if (EPI == 1) {
          const float t = val * val;
          const float z = val * fmaf(t, 0.07135481283f, 1.5957691216f);
          const float gl = val / (1.0f + __expf(-z));
          outb[(size_t)row * N + col] = __float2bfloat16(gl);
        } else {
          outf[(size_t)row * N + col] += val;
        }
      }
    }
  }
}

// ---------------- K3: MFMA windowed attention, ONE WAVE per (window, head) -------
// (unchanged from R5.)
__device__ __forceinline__ int regid(int v) { return v < 56 ? 0 : (v < 60 ? 1 : 2); }

__global__ __launch_bounds__(256, 2) void attn_kernel(
    const bf16* __restrict__ qkv, const float* __restrict__ tau,
    const float* __restrict__ rpb, bf16* __restrict__ outb)
{
  const int wv = threadIdx.x >> 6;
  const int lane = threadIdx.x & 63;
  const int q4 = lane >> 4, r = lane & 15;
  const int h = blockIdx.x * 4 + wv;       // head
  const int w = blockIdx.y;                // global window

  __shared__ bf16  pbuf[4][64 * 64];
  __shared__ float rpb_s[4][228];
  __shared__ float kscs[4][64];

  for (int t = lane; t < 225; t += 64)
    rpb_s[wv][t] = rpb[t * NHEADS + h];

  const size_t rowbase = ((size_t)w * 64) * 1152 + (size_t)h * 32;
  bf16x8 qf[4], kf[4];
  #pragma unroll
  for (int mi = 0; mi < 4; mi++) {
    const size_t ro = rowbase + (size_t)(mi * 16 + r) * 1152 + q4 * 8;
    qf[mi] = *(const bf16x8*)(qkv + ro);
    kf[mi] = *(const bf16x8*)(qkv + ro + 384);
  }

  const bf16* vbase = qkv + rowbase + 768;
  unsigned short vraw[2][2][8];
  #pragma unroll
  for (int ks = 0; ks < 2; ks++)
    #pragma unroll
    for (int nd = 0; nd < 2; nd++)
      #pragma unroll
      for (int t = 0; t < 8; t++)
        vraw[ks][nd][t] = *(const unsigned short*)(vbase +
            (size_t)(ks * 32 + q4 * 8 + t) * 1152 + nd * 16 + r);

  float qsc[4];
  {
    const float tinv = 1.0f / fmaxf(tau[h], 1e-3f);
    #pragma unroll
    for (int mi = 0; mi < 4; mi++) {
      float sq = 0.f, sk = 0.f;
      #pragma unroll
      for (int e = 0; e < 8; e++) {
        float a = bf2f(qf[mi][e]), b = bf2f(kf[mi][e]);
        sq = fmaf(a, a, sq); sk = fmaf(b, b, sk);
      }
      sq += __shfl_xor(sq, 16, 64); sq += __shfl_xor(sq, 32, 64);
      sk += __shfl_xor(sk, 16, 64); sk += __shfl_xor(sk, 32, 64);
      qsc[mi] = tinv / fmaxf(sqrtf(sq), 1e-12f);
      if (q4 == 0) kscs[wv][mi * 16 + r] = 1.0f / fmaxf(sqrtf(sk), 1e-12f);
    }
  }

  f32x4 sacc[4][4];
  #pragma unroll
  for (int a = 0; a < 4; a++)
    #pragma unroll
    for (int b = 0; b < 4; b++) sacc[a][b] = (f32x4){0.f, 0.f, 0.f, 0.f};
  #pragma unroll
  for (int mj = 0; mj < 4; mj++)
    #pragma unroll
    for (int mi = 0; mi < 4; mi++)
      sacc[mj][mi] = __builtin_amdgcn_mfma_f32_16x16x32_bf16(kf[mj], qf[mi], sacc[mj][mi], 0, 0, 0);

  const int wi = w & 63, wy = wi >> 3, wx = wi & 7;
  int byi[4], regi[4];
  #pragma unroll
  for (int mi = 0; mi < 4; mi++) {
    const int i = mi * 16 + r, iy = i >> 3, ix = i & 7;
    byi[mi]  = (iy + 7) * 15 + (ix + 7);
    regi[mi] = regid(wy * 8 + iy) * 3 + regid(wx * 8 + ix);
  }
  float kscv[4][4];
  #pragma unroll
  for (int mj = 0; mj < 4; mj++)
    #pragma unroll
    for (int reg = 0; reg < 4; reg++)
      kscv[mj][reg] = kscs[wv][mj * 16 + q4 * 4 + reg];

  float mx[4] = {-3e38f, -3e38f, -3e38f, -3e38f};
  #pragma unroll
  for (int mj = 0; mj < 4; mj++) {
    #pragma unroll
    for (int reg = 0; reg < 4; reg++) {
      const int j = mj * 16 + q4 * 4 + reg;
      const int jy = j >> 3, jx = j & 7;
      const int offj = jy * 15 + jx;
      const int regj = regid(wy * 8 + jy) * 3 + regid(wx * 8 + jx);
      const float kv = kscv[mj][reg];
      #pragma unroll
      for (int mi = 0; mi < 4; mi++) {
        float v = sacc[mj][mi][reg] * (qsc[mi] * kv) + rpb_s[wv][byi[mi] - offj];
        if (regj != regi[mi]) v -= 1e9f;
        sacc[mj][mi][reg] = v;
        mx[mi] = fmaxf(mx[mi], v);
      }
    }
  }
  float sum[4] = {0.f, 0.f, 0.f, 0.f};
  #pragma unroll
  for (int mi = 0; mi < 4; mi++) {
    mx[mi] = fmaxf(mx[mi], __shfl_xor(mx[mi], 16, 64));
    mx[mi] = fmaxf(mx[mi], __shfl_xor(mx[mi], 32, 64));
  }
  #pragma unroll
  for (int mj = 0; mj < 4; mj++)
    #pragma unroll
    for (int mi = 0; mi < 4; mi++)
      #pragma unroll
      for (int reg = 0; reg < 4; reg++) {
        float p = __expf(sacc[mj][mi][reg] - mx[mi]);
        sacc[mj][mi][reg] = p;
        sum[mi] += p;
      }
  float rinv[4];
  #pragma unroll
  for (int mi = 0; mi < 4; mi++) {
    sum[mi] += __shfl_xor(sum[mi], 16, 64);
    sum[mi] += __shfl_xor(sum[mi], 32, 64);
    rinv[mi] = 1.0f / sum[mi];
  }

  #pragma unroll
  for (int mj = 0; mj < 4; mj++) {
    #pragma unroll
    for (int mi = 0; mi < 4; mi++) {
      const int i = mi * 16 + r;
      const int cs = (mj * 4 + q4) ^ r;
      uint2 d;
      d.x = f2u(sacc[mj][mi][0] * rinv[mi]) | (f2u(sacc[mj][mi][1] * rinv[mi]) << 16);
      d.y = f2u(sacc[mj][mi][2] * rinv[mi]) | (f2u(sacc[mj][mi][3] * rinv[mi]) << 16);
      *(uint2*)(&pbuf[wv][i * 64 + cs * 4]) = d;
    }
  }

  bf16x8 vf[2][2];
  #pragma unroll
  for (int ks = 0; ks < 2; ks++)
    #pragma unroll
    for (int nd = 0; nd < 2; nd++) {
      union { unsigned int u[4]; bf16x8 v; } t;
      #pragma unroll
      for (int e = 0; e < 4; e++)
        t.u[e] = (unsigned int)vraw[ks][nd][2 * e] |
                 ((unsigned int)vraw[ks][nd][2 * e + 1] << 16);
      vf[ks][nd] = t.v;
    }

  f32x4 oacc[4][2];
  #pragma unroll
  for (int a = 0; a < 4; a++)
    #pragma unroll
    for (int b = 0; b < 2; b++) oacc[a][b] = (f32x4){0.f, 0.f, 0.f, 0.f};
  #pragma unroll
  for (int mi = 0; mi < 4; mi++) {
    const int i = mi * 16 + r;
    #pragma unroll
    for (int ks = 0; ks < 2; ks++) {
      const int c1 = (ks * 8 + q4 * 2) ^ r;
      const int c2 = (ks * 8 + q4 * 2 + 1) ^ r;
      union { unsigned int u[4]; bf16x8 v; } pf;
      uint2 lo = *(const uint2*)(&pbuf[wv][i * 64 + c1 * 4]);
      uint2 hi = *(const uint2*)(&pbuf[wv][i * 64 + c2 * 4]);
      pf.u[0] = lo.x; pf.u[1] = lo.y; pf.u[2] = hi.x; pf.u[3] = hi.y;
      #pragma unroll
      for (int nd = 0; nd < 2; nd++)
        oacc[mi][nd] = __builtin_amdgcn_mfma_f32_16x16x32_bf16(pf.v, vf[ks][nd], oacc[mi][nd], 0, 0, 0);
    }
  }

  #pragma unroll
  for (int mi = 0; mi < 4; mi++)
    #pragma unroll
    for (int nd = 0; nd < 2; nd++)
      #pragma unroll
      for (int reg = 0; reg < 4; reg++) {
        const int i = mi * 16 + q4 * 4 + reg;
        outb[((size_t)w * 64 + i) * DIM + h * 32 + nd * 16 + r] =
            __float2bfloat16(oacc[mi][nd][reg]);
      }
}

// ---------------- host launch ----------------
extern "C" void kernel_launch(void* const* d_in, const int* in_sizes, int n_in,
                              void* d_out, int out_size, void* d_ws, size_t ws_size,
                              hipStream_t stream) {
  const float* x      = (const float*)d_in[0];
  const float* ln1_g  = (const float*)d_in[3];
  const float* ln1_b  = (const float*)d_in[4];
  const float* qkv_w  = (const float*)d_in[5];
  const float* qkv_b  = (const float*)d_in[6];
  const float* proj_w = (const float*)d_in[7];
  const float* proj_b = (const float*)d_in[8];
  const float* tau    = (const float*)d_in[9];
  const float* rpb    = (const float*)d_in[10];
  const float* ln2_g  = (const float*)d_in[11];
  const float* ln2_b  = (const float*)d_in[12];
  const float* fc1_w  = (const float*)d_in[13];
  const float* fc1_b  = (const float*)d_in[14];
  const float* fc2_w  = (const float*)d_in[15];
  const float* fc2_b  = (const float*)d_in[16];
  float* out = (float*)d_out;
  char* ws = (char*)d_ws;

  // workspace (peak ~256 MiB, buffers reused; lifetimes commented)
  bf16* wT_qkv  = (bf16*)(ws + 0);
  bf16* wT_proj = (bf16*)(ws + 884736);
  bf16* wT_fc1  = (bf16*)(ws + 1179648);
  bf16* wT_fc2  = (bf16*)(ws + 2359296);
  bf16* winb    = (bf16*)(ws + 4194304);      // LN1 out; dead after qkv GEMM
  bf16* qkvb    = (bf16*)(ws + 54525952);     // qkv out; dead after attn
  bf16* attnb   = (bf16*)(ws + 205520896);    // attn out; dead after proj
  bf16* xn2b    = winb;                        // LN2 out (reuse winb)
  bf16* projb   = qkvb;                        // proj out (reuse qkvb, 50 MB)
  bf16* hb      = qkvb;                        // fc1 out (reuse after projb dead)

  wconv_kernel<<<(384 * 1152 + 255) / 256, 256, 0, stream>>>(qkv_w, wT_qkv, 384, 1152);
  wconv_kernel<<<(384 * 384 + 255) / 256, 256, 0, stream>>>(proj_w, wT_proj, 384, 384);
  wconv_kernel<<<(384 * 1536 + 255) / 256, 256, 0, stream>>>(fc1_w, wT_fc1, 384, 1536);
  wconv_kernel<<<(1536 * 384 + 255) / 256, 256, 0, stream>>>(fc2_w, wT_fc2, 1536, 384);

  // K1: LN1 + roll + window partition (wave-per-row)
  ln1_kernel<<<MTOT / 4, 256, 0, stream>>>(x, ln1_g, ln1_b, winb);
  // K2: qkv GEMM
  gemm_bt<0><<<(MTOT / 128) * (1152 / 128), 512, 0, stream>>>(
      winb, wT_qkv, qkv_b, qkvb, nullptr, nullptr, MTOT, 1152, 384, 1152 / 128);
  // K3: attention
  attn_kernel<<<dim3(3, 1024), 256, 0, stream>>>(qkvb, tau, rpb, attnb);
  // K4: proj GEMM, pure bf16 row-major out (scatter moved to K5)
  gemm_bt<0><<<(MTOT / 128) * (384 / 128), 512, 0, stream>>>(
      attnb, wT_proj, proj_b, projb, nullptr, nullptr, MTOT, 384, 384, 384 / 128);
  // K5: fused residual + window-reverse/roll gather + LN2
  resid_ln2_kernel<<<MTOT / 4, 256, 0, stream>>>(x, projb, ln2_g, ln2_b, out, xn2b);
  // K6: fc1 + GELU
  gemm_bt<1><<<(MTOT / 128) * (HID / 128), 512, 0, stream>>>(
      xn2b, wT_fc1, fc1_b, hb, nullptr, nullptr, MTOT, HID, 384, HID / 128);
  // K7: fc2 += into out
  gemm_bt<3><<<(MTOT / 128) * (384 / 128), 512, 0, stream>>>(
      hb, wT_fc2, fc2_b, nullptr, out, nullptr, MTOT, 384, HID, 384 / 128);
}